// Round 2
// baseline (648.844 us; speedup 1.0000x reference)
//
#include <hip/hip_runtime.h>
#include <stdint.h>

#define NB 4
#define CC 256
#define NN 4096   // H*W = 64*64

typedef __attribute__((ext_vector_type(8))) short short8;   // 8 x bf16 (4 VGPR) MFMA frag
typedef __attribute__((ext_vector_type(4))) short shortx4;  // 4 x bf16 packed store
typedef __attribute__((ext_vector_type(4))) float floatx4;  // MFMA acc
typedef __attribute__((ext_vector_type(4))) int intx4;      // 16B copy

__device__ __forceinline__ short f2bf(float f) {
  unsigned u = __float_as_uint(f);
  unsigned r = (u + 0x7fffu + ((u >> 16) & 1u)) >> 16;  // round-to-nearest-even
  return (short)r;
}
__device__ __forceinline__ float bf2f(short h) {
  return __uint_as_float(((unsigned)(unsigned short)h) << 16);
}

// ---------------------------------------------------------------------------
// Transpose + fp32->bf16 hi/lo split: F [b][c][n] fp32 -> Xhi,Xlo [b][n][c]
// grid (64 n-tiles, 4 c-tiles, 8 = b*2+which), 256 threads
// ---------------------------------------------------------------------------
__global__ __launch_bounds__(256) void k_transpose(const float* __restrict__ Fc,
                                                   const float* __restrict__ Fs,
                                                   short* __restrict__ XctH, short* __restrict__ XctL,
                                                   short* __restrict__ XstH, short* __restrict__ XstL) {
  __shared__ float t[64][65];
  const int nt = blockIdx.x, ct = blockIdx.y, bz = blockIdx.z;
  const int b = bz >> 1;
  const float* src = ((bz & 1) ? Fs : Fc) + (size_t)b * CC * NN;
  short* dstH = ((bz & 1) ? XstH : XctH) + (size_t)b * NN * CC;
  short* dstL = ((bz & 1) ? XstL : XctL) + (size_t)b * NN * CC;
  const int tid = threadIdx.x;
  const int n0 = nt * 64, c0 = ct * 64;
  const int col = tid & 63, row4 = tid >> 6;
#pragma unroll
  for (int i = 0; i < 16; i++) {
    int c = row4 + i * 4;
    t[c][col] = src[(size_t)(c0 + c) * NN + n0 + col];  // coalesced over n
  }
  __syncthreads();
#pragma unroll
  for (int i = 0; i < 16; i++) {
    int n = row4 + i * 4;
    float x = t[col][n];
    short h = f2bf(x);
    dstH[(size_t)(n0 + n) * CC + c0 + col] = h;
    dstL[(size_t)(n0 + n) * CC + c0 + col] = f2bf(x - bf2f(h));
  }
}

// Weights fp32 -> bf16 hi/lo (4 x 256x256). grid 256, 256 threads.
__global__ __launch_bounds__(256) void k_wconv(const float* __restrict__ w0, const float* __restrict__ w1,
                                               const float* __restrict__ w2, const float* __restrict__ w3,
                                               short* __restrict__ h0, short* __restrict__ h1,
                                               short* __restrict__ h2, short* __restrict__ h3,
                                               short* __restrict__ l0, short* __restrict__ l1,
                                               short* __restrict__ l2, short* __restrict__ l3) {
  int i = blockIdx.x * 256 + threadIdx.x;
  float a = w0[i], b = w1[i], c = w2[i], d = w3[i];
  short ha = f2bf(a), hb = f2bf(b), hc = f2bf(c), hd = f2bf(d);
  h0[i] = ha; h1[i] = hb; h2[i] = hc; h3[i] = hd;
  l0[i] = f2bf(a - bf2f(ha)); l1[i] = f2bf(b - bf2f(hb));
  l2[i] = f2bf(c - bf2f(hc)); l3[i] = f2bf(d - bf2f(hd));
}

// ---------------------------------------------------------------------------
// Projection GEMM: D[m][n] = sum_c A[m][c]*B[n][c], K=256.
// PREC=1: 3-term hi/lo split MFMA (fp32-quality), out written as hi+lo planes.
// MODE 0: out bf16 at out[n*256 + m]   (Q,K: m=d, n=spatial)   -> [n][d]
// MODE 1: out bf16 at out[n*4096 + m]  (V:  m=spatial, n=d)    -> [d][n]
// MODE 2: like 1 but fp32 (final conv output)
// grid (Mtiles*Ntiles, batch), 256 threads
// ---------------------------------------------------------------------------
template <int MODE, int PREC>
__global__ __launch_bounds__(256, 2) void k_proj(const short* __restrict__ A, const short* __restrict__ Al,
                                                 long aStride,
                                                 const short* __restrict__ Bm, const short* __restrict__ Bl,
                                                 long bStride,
                                                 const float* __restrict__ bias,
                                                 void* __restrict__ out, void* __restrict__ outLo,
                                                 long oStride, int Ntiles) {
  constexpr int NP = PREC ? 2 : 1;
  __shared__ short As[NP][128][40];  // 80B rows: 16B-aligned, ~2-way banks
  __shared__ short Bs[NP][128][40];
  const int bz = blockIdx.y;
  const int mt = blockIdx.x / Ntiles, nt = blockIdx.x % Ntiles;
  const int m0 = mt * 128, n0 = nt * 128;
  const int tid = threadIdx.x;
  const int wave = tid >> 6, lane = tid & 63, quad = lane >> 4, l15 = lane & 15;
  const int wm = (wave >> 1) * 64, wn = (wave & 1) * 64;

  floatx4 acc[4][4];
#pragma unroll
  for (int i = 0; i < 4; i++)
#pragma unroll
    for (int j = 0; j < 4; j++) acc[i][j] = (floatx4){0.f, 0.f, 0.f, 0.f};

  const int srow = tid >> 1;
  const int shalf = (tid & 1) * 16;
  const size_t aOff = (size_t)bz * aStride + (size_t)(m0 + srow) * 256 + shalf;
  const size_t bOff = (size_t)bz * bStride + (size_t)(n0 + srow) * 256 + shalf;

  for (int kk = 0; kk < 256; kk += 32) {
    intx4 va0 = *(const intx4*)(A + aOff + kk);
    intx4 va1 = *(const intx4*)(A + aOff + kk + 8);
    intx4 vb0 = *(const intx4*)(Bm + bOff + kk);
    intx4 vb1 = *(const intx4*)(Bm + bOff + kk + 8);
    intx4 va2, va3, vb2, vb3;
    if (PREC) {
      va2 = *(const intx4*)(Al + aOff + kk);
      va3 = *(const intx4*)(Al + aOff + kk + 8);
      vb2 = *(const intx4*)(Bl + bOff + kk);
      vb3 = *(const intx4*)(Bl + bOff + kk + 8);
    }
    __syncthreads();
    *(intx4*)&As[0][srow][shalf] = va0;
    *(intx4*)&As[0][srow][shalf + 8] = va1;
    *(intx4*)&Bs[0][srow][shalf] = vb0;
    *(intx4*)&Bs[0][srow][shalf + 8] = vb1;
    if (PREC) {
      *(intx4*)&As[NP - 1][srow][shalf] = va2;
      *(intx4*)&As[NP - 1][srow][shalf + 8] = va3;
      *(intx4*)&Bs[NP - 1][srow][shalf] = vb2;
      *(intx4*)&Bs[NP - 1][srow][shalf + 8] = vb3;
    }
    __syncthreads();
    short8 afh[4], bfh[4], afl[4], bfl[4];
#pragma unroll
    for (int mb = 0; mb < 4; mb++) afh[mb] = *(const short8*)&As[0][wm + mb * 16 + l15][quad * 8];
#pragma unroll
    for (int nb = 0; nb < 4; nb++) bfh[nb] = *(const short8*)&Bs[0][wn + nb * 16 + l15][quad * 8];
    if (PREC) {
#pragma unroll
      for (int mb = 0; mb < 4; mb++) afl[mb] = *(const short8*)&As[NP - 1][wm + mb * 16 + l15][quad * 8];
#pragma unroll
      for (int nb = 0; nb < 4; nb++) bfl[nb] = *(const short8*)&Bs[NP - 1][wn + nb * 16 + l15][quad * 8];
    }
#pragma unroll
    for (int mb = 0; mb < 4; mb++)
#pragma unroll
      for (int nb = 0; nb < 4; nb++) {
        acc[mb][nb] = __builtin_amdgcn_mfma_f32_16x16x32_bf16(afh[mb], bfh[nb], acc[mb][nb], 0, 0, 0);
        if (PREC) {
          acc[mb][nb] = __builtin_amdgcn_mfma_f32_16x16x32_bf16(afh[mb], bfl[nb], acc[mb][nb], 0, 0, 0);
          acc[mb][nb] = __builtin_amdgcn_mfma_f32_16x16x32_bf16(afl[mb], bfh[nb], acc[mb][nb], 0, 0, 0);
        }
      }
  }

  if (MODE == 0) {
    short* op = (short*)out + (size_t)bz * oStride;
    short* ol = (short*)outLo + (size_t)bz * oStride;
#pragma unroll
    for (int mb = 0; mb < 4; mb++) {
      int d0 = m0 + wm + mb * 16 + quad * 4;  // m-side = channel d
      float b0 = bias[d0], b1 = bias[d0 + 1], b2 = bias[d0 + 2], b3 = bias[d0 + 3];
#pragma unroll
      for (int nb = 0; nb < 4; nb++) {
        int n_ = n0 + wn + nb * 16 + l15;  // n-side = spatial
        float v0 = acc[mb][nb][0] + b0, v1 = acc[mb][nb][1] + b1;
        float v2 = acc[mb][nb][2] + b2, v3 = acc[mb][nb][3] + b3;
        shortx4 pk;
        pk[0] = f2bf(v0); pk[1] = f2bf(v1); pk[2] = f2bf(v2); pk[3] = f2bf(v3);
        *(shortx4*)(op + (size_t)n_ * CC + d0) = pk;  // 8B packed
        if (PREC) {
          shortx4 pl;
          pl[0] = f2bf(v0 - bf2f(pk[0])); pl[1] = f2bf(v1 - bf2f(pk[1]));
          pl[2] = f2bf(v2 - bf2f(pk[2])); pl[3] = f2bf(v3 - bf2f(pk[3]));
          *(shortx4*)(ol + (size_t)n_ * CC + d0) = pl;
        }
      }
    }
  } else {
#pragma unroll
    for (int mb = 0; mb < 4; mb++) {
      int nq0 = m0 + wm + mb * 16 + quad * 4;  // m-side = spatial
#pragma unroll
      for (int nb = 0; nb < 4; nb++) {
        int d = n0 + wn + nb * 16 + l15;  // n-side = channel d
        float bv = bias[d];
        if (MODE == 1) {
          short* op = (short*)out + (size_t)bz * oStride;
          shortx4 pk;
          pk[0] = f2bf(acc[mb][nb][0] + bv);
          pk[1] = f2bf(acc[mb][nb][1] + bv);
          pk[2] = f2bf(acc[mb][nb][2] + bv);
          pk[3] = f2bf(acc[mb][nb][3] + bv);
          *(shortx4*)(op + (size_t)d * NN + nq0) = pk;
        } else {
          float* op = (float*)out + (size_t)bz * oStride;
          floatx4 pk;
          pk[0] = acc[mb][nb][0] + bv;
          pk[1] = acc[mb][nb][1] + bv;
          pk[2] = acc[mb][nb][2] + bv;
          pk[3] = acc[mb][nb][3] + bv;
          *(floatx4*)(op + (size_t)d * NN + nq0) = pk;  // 16B
        }
      }
    }
  }
}

// ---------------------------------------------------------------------------
// Flash attention (unscaled logits): Q,K hi/lo [b][n][c] bf16 pairs,
// Vt [b][c][n] bf16 -> O [b][n][c] bf16, O = softmax(Q K^T) V.
// Logits via 3-term hi/lo MFMA (fp32-quality); fp32 online softmax.
// Tq=32/block, Tk=32/iter. grid (128, batch), 256 threads.
// ---------------------------------------------------------------------------
__global__ __launch_bounds__(256, 2) void k_attn(const short* __restrict__ Qh, const short* __restrict__ Ql,
                                                 const short* __restrict__ Kh, const short* __restrict__ Kl,
                                                 const short* __restrict__ Vt, short* __restrict__ O) {
  __shared__ short Klds[2][32][264];  // hi/lo; 528B rows (16B-aligned)
  __shared__ short Vlds[256][40];     // 80B rows
  __shared__ short Plds[32][56];      // 112B rows
  __shared__ float pmaxL[2][32];
  __shared__ float psumL[2][32];
  __shared__ float alphaL[32];
  __shared__ float lL[32];

  const int b = blockIdx.y;
  const int q0 = blockIdx.x * 32;
  const short* Qhb = Qh + (size_t)b * NN * CC;
  const short* Qlb = Ql + (size_t)b * NN * CC;
  const short* Khb = Kh + (size_t)b * NN * CC;
  const short* Klb = Kl + (size_t)b * NN * CC;
  const short* Vb = Vt + (size_t)b * CC * NN;
  short* Ob = O + (size_t)b * NN * CC;

  const int tid = threadIdx.x;
  const int wave = tid >> 6, lane = tid & 63, quad = lane >> 4, l15 = lane & 15;
  const int s = wave & 1, kb = wave >> 1;

  // Q fragments (hi/lo) for this wave's 16-q strip — registers, whole kernel
  short8 qfh[8], qfl[8];
#pragma unroll
  for (int cs = 0; cs < 8; cs++) {
    size_t off = (size_t)(q0 + s * 16 + l15) * CC + cs * 32 + quad * 8;
    qfh[cs] = *(const short8*)(Qhb + off);
    qfl[cs] = *(const short8*)(Qlb + off);
  }

  floatx4 Oacc[2][4];  // [qb][cb], wave owns channels wave*64..+64
#pragma unroll
  for (int i = 0; i < 2; i++)
#pragma unroll
    for (int j = 0; j < 4; j++) Oacc[i][j] = (floatx4){0.f, 0.f, 0.f, 0.f};

  float m_run[4], l_run[4], al[4];
#pragma unroll
  for (int r = 0; r < 4; r++) { m_run[r] = -1e30f; l_run[r] = 0.f; }

  const int krow = tid >> 3;        // 32 K rows, 8 threads/row
  const int kcol = (tid & 7) * 32;  // 64B per thread per plane

  for (int kt = 0; kt < 128; kt++) {
    const int k0 = kt * 32;
    // issue global loads before barrier (overlaps prior S/PV)
    const short* gkh = Khb + (size_t)(k0 + krow) * CC + kcol;
    const short* gkl = Klb + (size_t)(k0 + krow) * CC + kcol;
    intx4 kh0 = *(const intx4*)gkh;
    intx4 kh1 = *(const intx4*)(gkh + 8);
    intx4 kh2 = *(const intx4*)(gkh + 16);
    intx4 kh3 = *(const intx4*)(gkh + 24);
    intx4 kl0 = *(const intx4*)gkl;
    intx4 kl1 = *(const intx4*)(gkl + 8);
    intx4 kl2 = *(const intx4*)(gkl + 16);
    intx4 kl3 = *(const intx4*)(gkl + 24);
    const short* gv = Vb + (size_t)tid * NN + k0;  // Vt row per thread (64B)
    intx4 vv0 = *(const intx4*)gv;
    intx4 vv1 = *(const intx4*)(gv + 8);
    intx4 vv2 = *(const intx4*)(gv + 16);
    intx4 vv3 = *(const intx4*)(gv + 24);
    __syncthreads();  // A: prior S/PV reads of Klds/Vlds done
    *(intx4*)&Klds[0][krow][kcol + 0] = kh0;
    *(intx4*)&Klds[0][krow][kcol + 8] = kh1;
    *(intx4*)&Klds[0][krow][kcol + 16] = kh2;
    *(intx4*)&Klds[0][krow][kcol + 24] = kh3;
    *(intx4*)&Klds[1][krow][kcol + 0] = kl0;
    *(intx4*)&Klds[1][krow][kcol + 8] = kl1;
    *(intx4*)&Klds[1][krow][kcol + 16] = kl2;
    *(intx4*)&Klds[1][krow][kcol + 24] = kl3;
    *(intx4*)&Vlds[tid][0] = vv0;
    *(intx4*)&Vlds[tid][8] = vv1;
    *(intx4*)&Vlds[tid][16] = vv2;
    *(intx4*)&Vlds[tid][24] = vv3;
    __syncthreads();  // B

    // S: this wave's [16q x 16k] tile, contraction over 256 c, hi/lo 3-term
    floatx4 sc = {0.f, 0.f, 0.f, 0.f};
#pragma unroll
    for (int cs = 0; cs < 8; cs++) {
      short8 kfh = *(const short8*)&Klds[0][kb * 16 + l15][cs * 32 + quad * 8];
      short8 kfl = *(const short8*)&Klds[1][kb * 16 + l15][cs * 32 + quad * 8];
      sc = __builtin_amdgcn_mfma_f32_16x16x32_bf16(qfh[cs], kfh, sc, 0, 0, 0);
      sc = __builtin_amdgcn_mfma_f32_16x16x32_bf16(qfh[cs], kfl, sc, 0, 0, 0);
      sc = __builtin_amdgcn_mfma_f32_16x16x32_bf16(qfl[cs], kfh, sc, 0, 0, 0);
    }
    // partial row-max over the 16 key-lanes
#pragma unroll
    for (int r = 0; r < 4; r++) {
      float v = sc[r];
      v = fmaxf(v, __shfl_xor(v, 1));
      v = fmaxf(v, __shfl_xor(v, 2));
      v = fmaxf(v, __shfl_xor(v, 4));
      v = fmaxf(v, __shfl_xor(v, 8));
      if (l15 == 0) pmaxL[kb][s * 16 + quad * 4 + r] = v;
    }
    __syncthreads();  // C
#pragma unroll
    for (int r = 0; r < 4; r++) {
      const int qr = s * 16 + quad * 4 + r;
      float mN = fmaxf(m_run[r], fmaxf(pmaxL[0][qr], pmaxL[1][qr]));
      al[r] = __expf(m_run[r] - mN);
      m_run[r] = mN;
      float p = __expf(sc[r] - mN);
      float sum = p;
      sum += __shfl_xor(sum, 1);
      sum += __shfl_xor(sum, 2);
      sum += __shfl_xor(sum, 4);
      sum += __shfl_xor(sum, 8);
      Plds[qr][kb * 16 + l15] = f2bf(p);
      if (l15 == 0) {
        psumL[kb][qr] = sum;
        if (kb == 0) alphaL[qr] = al[r];
      }
    }
    __syncthreads();  // D
#pragma unroll
    for (int r = 0; r < 4; r++) {
      const int qr = s * 16 + quad * 4 + r;
      l_run[r] = l_run[r] * al[r] + psumL[0][qr] + psumL[1][qr];
    }
    // PV: O[32q x 64c slice] += P[32q x 32k] * V[32k x 64c]
    short8 vf[4];
#pragma unroll
    for (int cb = 0; cb < 4; cb++)
      vf[cb] = *(const short8*)&Vlds[wave * 64 + cb * 16 + l15][quad * 8];
#pragma unroll
    for (int qb = 0; qb < 2; qb++) {
      short8 pf = *(const short8*)&Plds[qb * 16 + l15][quad * 8];
      float a0 = alphaL[qb * 16 + quad * 4 + 0];
      float a1 = alphaL[qb * 16 + quad * 4 + 1];
      float a2 = alphaL[qb * 16 + quad * 4 + 2];
      float a3 = alphaL[qb * 16 + quad * 4 + 3];
#pragma unroll
      for (int cb = 0; cb < 4; cb++) {
        floatx4 t = Oacc[qb][cb];
        t[0] *= a0; t[1] *= a1; t[2] *= a2; t[3] *= a3;
        Oacc[qb][cb] = __builtin_amdgcn_mfma_f32_16x16x32_bf16(pf, vf[cb], t, 0, 0, 0);
      }
    }
  }

  // epilogue: 1/l, transpose through LDS (reuse Klds[0]), coalesced store
  if (kb == 0 && l15 == 0) {
#pragma unroll
    for (int r = 0; r < 4; r++) lL[s * 16 + quad * 4 + r] = l_run[r];
  }
  __syncthreads();
  short(*Ol)[264] = Klds[0];
#pragma unroll
  for (int qb = 0; qb < 2; qb++) {
    float inv0 = 1.f / lL[qb * 16 + quad * 4 + 0];
    float inv1 = 1.f / lL[qb * 16 + quad * 4 + 1];
    float inv2 = 1.f / lL[qb * 16 + quad * 4 + 2];
    float inv3 = 1.f / lL[qb * 16 + quad * 4 + 3];
#pragma unroll
    for (int cb = 0; cb < 4; cb++) {
      int c = wave * 64 + cb * 16 + l15;
      Ol[qb * 16 + quad * 4 + 0][c] = f2bf(Oacc[qb][cb][0] * inv0);
      Ol[qb * 16 + quad * 4 + 1][c] = f2bf(Oacc[qb][cb][1] * inv1);
      Ol[qb * 16 + quad * 4 + 2][c] = f2bf(Oacc[qb][cb][2] * inv2);
      Ol[qb * 16 + quad * 4 + 3][c] = f2bf(Oacc[qb][cb][3] * inv3);
    }
  }
  __syncthreads();
  const int orow = tid >> 3;
  const int ocol = (tid & 7) * 32;
#pragma unroll
  for (int i = 0; i < 4; i++)
    *(intx4*)(Ob + (size_t)(q0 + orow) * CC + ocol + i * 8) =
        *(const intx4*)&Ol[orow][ocol + i * 8];
}

// ---------------------------------------------------------------------------
extern "C" void kernel_launch(void* const* d_in, const int* in_sizes, int n_in,
                              void* d_out, int out_size, void* d_ws, size_t ws_size,
                              hipStream_t stream) {
  const float* Fc = (const float*)d_in[0];
  const float* Fs = (const float*)d_in[1];
  const float* Wf = (const float*)d_in[2];
  const float* bf_ = (const float*)d_in[3];
  const float* Wg = (const float*)d_in[4];
  const float* bg = (const float*)d_in[5];
  const float* Wh = (const float*)d_in[6];
  const float* bh = (const float*)d_in[7];
  const float* Wo = (const float*)d_in[8];
  const float* bo = (const float*)d_in[9];

  char* ws = (char*)d_ws;
  const size_t sz = (size_t)NB * NN * CC * sizeof(short);  // 8 MB per plane
  short* XctH = (short*)(ws + 0 * sz);
  short* XctL = (short*)(ws + 1 * sz);  // reused for O after Q proj
  short* XstH = (short*)(ws + 2 * sz);
  short* XstL = (short*)(ws + 3 * sz);
  short* QbH  = (short*)(ws + 4 * sz);
  short* QbL  = (short*)(ws + 5 * sz);
  short* KbH  = (short*)(ws + 6 * sz);
  short* KbL  = (short*)(ws + 7 * sz);
  short* Vtb  = (short*)(ws + 8 * sz);
  short* Wfb = (short*)(ws + 9 * sz);   // 8 weight planes x 128 KB
  short* Wgb = Wfb + 65536;
  short* Whb = Wgb + 65536;
  short* Wob = Whb + 65536;
  short* WfbL = Wob + 65536;
  short* WgbL = WfbL + 65536;
  short* WhbL = WgbL + 65536;
  short* WobL = WhbL + 65536;
  short* Ob = XctL;  // O reuses Xct_lo (dead after Q projection)

  const long bs = (long)NN * CC;  // per-batch stride (elements)

  k_transpose<<<dim3(64, 4, 8), 256, 0, stream>>>(Fc, Fs, XctH, XctL, XstH, XstL);
  k_wconv<<<dim3(256), 256, 0, stream>>>(Wf, Wg, Wh, Wo, Wfb, Wgb, Whb, Wob,
                                         WfbL, WgbL, WhbL, WobL);
  // Fq -> Q[n][d] hi/lo:  A=Wf (M=256, 2 Mtiles), B=Xct (N=4096, 32 Ntiles)
  k_proj<0, 1><<<dim3(64, NB), 256, 0, stream>>>(Wfb, WfbL, 0, XctH, XctL, bs, bf_, QbH, QbL, bs, 32);
  // G  -> K[n][d] hi/lo
  k_proj<0, 1><<<dim3(64, NB), 256, 0, stream>>>(Wgb, WgbL, 0, XstH, XstL, bs, bg, KbH, KbL, bs, 32);
  // Hv -> Vt[d][n] (single bf16): A=Xst (M=4096, 32 Mtiles), B=Wh (N=256, 2 Ntiles)
  k_proj<1, 0><<<dim3(64, NB), 256, 0, stream>>>(XstH, nullptr, bs, Whb, nullptr, 0, bh, Vtb, nullptr, bs, 2);
  // attention: O[n][c] = softmax(Q K^T) V
  k_attn<<<dim3(128, NB), 256, 0, stream>>>(QbH, QbL, KbH, KbL, Vtb, Ob);
  // final conv: out[d][n] fp32 = Wo . O^T + bo
  k_proj<2, 0><<<dim3(64, NB), 256, 0, stream>>>(Ob, nullptr, bs, Wob, nullptr, 0, bo, d_out, nullptr, bs, 2);
}

// Round 4
// 256.428 us; speedup vs baseline: 2.5303x; 2.5303x over previous
//
#include <hip/hip_runtime.h>
#include <stdint.h>

#define NB 4
#define CC 256
#define NN 4096   // H*W = 64*64

typedef __attribute__((ext_vector_type(8))) _Float16 half8;   // MFMA A/B frag (4 VGPR)
typedef __attribute__((ext_vector_type(4))) _Float16 half4;   // 8B packed store
typedef __attribute__((ext_vector_type(2))) _Float16 half2v;
typedef __attribute__((ext_vector_type(4))) float floatx4;    // 16x16 acc
typedef __attribute__((ext_vector_type(16))) float float16v;  // 32x32 acc
typedef __attribute__((ext_vector_type(4))) int intx4;        // 16B copy

// ---------------------------------------------------------------------------
// Transpose + fp32->fp16: F [b][c][n] f32 -> Xt [b][n][c] f16
// grid (64 n-tiles, 4 c-tiles, 8 = b*2+which), 256 threads
// ---------------------------------------------------------------------------
__global__ __launch_bounds__(256) void k_transpose(const float* __restrict__ Fc,
                                                   const float* __restrict__ Fs,
                                                   _Float16* __restrict__ Xct,
                                                   _Float16* __restrict__ Xst) {
  __shared__ float t[64][65];
  const int nt = blockIdx.x, ct = blockIdx.y, bz = blockIdx.z;
  const int b = bz >> 1;
  const float* src = ((bz & 1) ? Fs : Fc) + (size_t)b * CC * NN;
  _Float16* dst = ((bz & 1) ? Xst : Xct) + (size_t)b * NN * CC;
  const int tid = threadIdx.x;
  const int n0 = nt * 64, c0 = ct * 64;
  const int col = tid & 63, row4 = tid >> 6;
#pragma unroll
  for (int i = 0; i < 16; i++) {
    int c = row4 + i * 4;
    t[c][col] = src[(size_t)(c0 + c) * NN + n0 + col];  // coalesced over n
  }
  __syncthreads();
#pragma unroll
  for (int i = 0; i < 16; i++) {
    int n = row4 + i * 4;
    dst[(size_t)(n0 + n) * CC + c0 + col] = (_Float16)t[col][n];  // coalesced over c
  }
}

// Weights fp32 -> fp16 (4 x 256x256). grid 256, 256 threads.
__global__ __launch_bounds__(256) void k_wconv(const float* __restrict__ w0, const float* __restrict__ w1,
                                               const float* __restrict__ w2, const float* __restrict__ w3,
                                               _Float16* __restrict__ o0, _Float16* __restrict__ o1,
                                               _Float16* __restrict__ o2, _Float16* __restrict__ o3) {
  int i = blockIdx.x * 256 + threadIdx.x;
  o0[i] = (_Float16)w0[i]; o1[i] = (_Float16)w1[i];
  o2[i] = (_Float16)w2[i]; o3[i] = (_Float16)w3[i];
}

// ---------------------------------------------------------------------------
// Projection GEMM (fp16): D[m][n] = sum_c A[m][c]*B[n][c], K=256.
// MODE 0: out f16 at out[n*256 + m]   (Q,K: m=d, n=spatial)   -> [n][d]
// MODE 1: out f16 at out[n*4096 + m]  (V:  m=spatial, n=d)    -> [d][n]
// MODE 2: like 1 but fp32 (final conv output)
// grid (Mtiles*Ntiles, batch), 256 threads
// ---------------------------------------------------------------------------
template <int MODE>
__global__ __launch_bounds__(256, 2) void k_proj(const _Float16* __restrict__ A, long aStride,
                                                 const _Float16* __restrict__ Bm, long bStride,
                                                 const float* __restrict__ bias,
                                                 void* __restrict__ out, long oStride, int Ntiles) {
  __shared__ _Float16 As[128][40];  // 80B rows
  __shared__ _Float16 Bs[128][40];
  const int bz = blockIdx.y;
  const int mt = blockIdx.x / Ntiles, nt = blockIdx.x % Ntiles;
  const int m0 = mt * 128, n0 = nt * 128;
  const int tid = threadIdx.x;
  const int wave = tid >> 6, lane = tid & 63, quad = lane >> 4, l15 = lane & 15;
  const int wm = (wave >> 1) * 64, wn = (wave & 1) * 64;

  floatx4 acc[4][4];
#pragma unroll
  for (int i = 0; i < 4; i++)
#pragma unroll
    for (int j = 0; j < 4; j++) acc[i][j] = (floatx4){0.f, 0.f, 0.f, 0.f};

  const int srow = tid >> 1;
  const int shalf = (tid & 1) * 16;
  const size_t aOff = (size_t)bz * aStride + (size_t)(m0 + srow) * 256 + shalf;
  const size_t bOff = (size_t)bz * bStride + (size_t)(n0 + srow) * 256 + shalf;

  for (int kk = 0; kk < 256; kk += 32) {
    intx4 va0 = *(const intx4*)(A + aOff + kk);
    intx4 va1 = *(const intx4*)(A + aOff + kk + 8);
    intx4 vb0 = *(const intx4*)(Bm + bOff + kk);
    intx4 vb1 = *(const intx4*)(Bm + bOff + kk + 8);
    __syncthreads();
    *(intx4*)&As[srow][shalf] = va0;
    *(intx4*)&As[srow][shalf + 8] = va1;
    *(intx4*)&Bs[srow][shalf] = vb0;
    *(intx4*)&Bs[srow][shalf + 8] = vb1;
    __syncthreads();
    half8 af[4], bfr[4];
#pragma unroll
    for (int mb = 0; mb < 4; mb++) af[mb] = *(const half8*)&As[wm + mb * 16 + l15][quad * 8];
#pragma unroll
    for (int nb = 0; nb < 4; nb++) bfr[nb] = *(const half8*)&Bs[wn + nb * 16 + l15][quad * 8];
#pragma unroll
    for (int mb = 0; mb < 4; mb++)
#pragma unroll
      for (int nb = 0; nb < 4; nb++)
        acc[mb][nb] = __builtin_amdgcn_mfma_f32_16x16x32_f16(af[mb], bfr[nb], acc[mb][nb], 0, 0, 0);
  }

  if (MODE == 0) {
    _Float16* op = (_Float16*)out + (size_t)bz * oStride;
#pragma unroll
    for (int mb = 0; mb < 4; mb++) {
      int d0 = m0 + wm + mb * 16 + quad * 4;  // m-side = channel d
      float b0 = bias[d0], b1 = bias[d0 + 1], b2 = bias[d0 + 2], b3 = bias[d0 + 3];
#pragma unroll
      for (int nb = 0; nb < 4; nb++) {
        int n_ = n0 + wn + nb * 16 + l15;  // n-side = spatial
        half4 pk;
        pk[0] = (_Float16)(acc[mb][nb][0] + b0);
        pk[1] = (_Float16)(acc[mb][nb][1] + b1);
        pk[2] = (_Float16)(acc[mb][nb][2] + b2);
        pk[3] = (_Float16)(acc[mb][nb][3] + b3);
        *(half4*)(op + (size_t)n_ * CC + d0) = pk;  // 8B packed
      }
    }
  } else {
#pragma unroll
    for (int mb = 0; mb < 4; mb++) {
      int nq0 = m0 + wm + mb * 16 + quad * 4;  // m-side = spatial
#pragma unroll
      for (int nb = 0; nb < 4; nb++) {
        int d = n0 + wn + nb * 16 + l15;  // n-side = channel d
        float bv = bias[d];
        if (MODE == 1) {
          _Float16* op = (_Float16*)out + (size_t)bz * oStride;
          half4 pk;
          pk[0] = (_Float16)(acc[mb][nb][0] + bv);
          pk[1] = (_Float16)(acc[mb][nb][1] + bv);
          pk[2] = (_Float16)(acc[mb][nb][2] + bv);
          pk[3] = (_Float16)(acc[mb][nb][3] + bv);
          *(half4*)(op + (size_t)d * NN + nq0) = pk;
        } else {
          float* op = (float*)out + (size_t)bz * oStride;
          floatx4 pk;
          pk[0] = acc[mb][nb][0] + bv;
          pk[1] = acc[mb][nb][1] + bv;
          pk[2] = acc[mb][nb][2] + bv;
          pk[3] = acc[mb][nb][3] + bv;
          *(floatx4*)(op + (size_t)d * NN + nq0) = pk;  // 16B
        }
      }
    }
  }
}

// ---------------------------------------------------------------------------
// Flash attention v3 (fp16, unscaled logits), split-K x4.
// Q,K [b][n][c] f16, Vt [b][c][n] f16.
// Each wave owns 32 q rows (Tq=128/block), Tk=32 per iter, chunk=1024 k.
// S computed TRANSPOSED (S^T = K Q^T) via 32x32x16 MFMA -> softmax state is
// per-lane (q = lane&31): no cross-wave exchange, no softmax barriers.
// O accumulated transposed (O^T = V P^T): alpha-rescale is per-lane scalar.
// Outputs fp16 raw partials + (m,l) per q; merged by k_merge.
// grid (32 qtiles, 4 chunks, 4 b), 256 threads. 2 barriers/iter, prefetch.
// ---------------------------------------------------------------------------
__global__ __launch_bounds__(256, 2) void k_attn(const _Float16* __restrict__ Q,
                                                 const _Float16* __restrict__ K,
                                                 const _Float16* __restrict__ Vt,
                                                 _Float16* __restrict__ Op01,
                                                 _Float16* __restrict__ Op23,
                                                 float2* __restrict__ Ml) {
  __shared__ _Float16 Kl[32][264];     // 16.9 KB, row stride 33x16B (odd) -> conflict-free
  __shared__ _Float16 Vl[256][40];     // 20.5 KB, row stride 5x16B
  __shared__ _Float16 Pl[4][32][40];   // 10.2 KB per-wave P scratch (wave-sync, no barrier)
  __shared__ float Ot[4][32][33];      // 16.9 KB epilogue transpose

  const int qt = blockIdx.x, ck = blockIdx.y, b = blockIdx.z;
  const int tid = threadIdx.x;
  const int wave = tid >> 6, lane = tid & 63;
  const int ql = lane & 31, h = lane >> 5;
  const int q0 = qt * 128 + wave * 32;
  const _Float16* Qb = Q + (size_t)b * NN * CC;
  const _Float16* Kb = K + (size_t)b * NN * CC;
  const _Float16* Vb = Vt + (size_t)b * CC * NN;
  const int k_base = ck * 1024;

  // Q B-frags in registers: B[n=q=lane&31][c = h*8+j], 16 c-steps
  half8 qf[16];
#pragma unroll
  for (int cs = 0; cs < 16; cs++)
    qf[cs] = *(const half8*)(Qb + (size_t)(q0 + ql) * CC + cs * 16 + h * 8);

  float16v Oa[8];  // O^T acc: [cgroup] D[m=c][n=q]
#pragma unroll
  for (int g = 0; g < 8; g++)
#pragma unroll
    for (int i = 0; i < 16; i++) Oa[g][i] = 0.f;

  float m_run = -1e30f, l_run = 0.f;

  // staging mappings (conflict-free; see bank analysis)
  const int krow = tid >> 4;          // 0..15 (+16 second pass)
  const int kcol = (tid & 15) * 16;   // halves
  const int vrow = tid >> 2;          // 0..63 (+64p)
  const int vcol = (tid & 3) * 8;     // halves

  intx4 kpre[4], vpre[4];
  {
    const _Float16* g = Kb + (size_t)(k_base) * CC;
    kpre[0] = *(const intx4*)(g + (size_t)krow * CC + kcol);
    kpre[1] = *(const intx4*)(g + (size_t)krow * CC + kcol + 8);
    kpre[2] = *(const intx4*)(g + (size_t)(krow + 16) * CC + kcol);
    kpre[3] = *(const intx4*)(g + (size_t)(krow + 16) * CC + kcol + 8);
#pragma unroll
    for (int p = 0; p < 4; p++)
      vpre[p] = *(const intx4*)(Vb + (size_t)(vrow + 64 * p) * NN + k_base + vcol);
  }

  for (int t = 0; t < 32; t++) {
    __syncthreads();  // prior reads of Kl/Vl done
    *(intx4*)&Kl[krow][kcol] = kpre[0];
    *(intx4*)&Kl[krow][kcol + 8] = kpre[1];
    *(intx4*)&Kl[krow + 16][kcol] = kpre[2];
    *(intx4*)&Kl[krow + 16][kcol + 8] = kpre[3];
#pragma unroll
    for (int p = 0; p < 4; p++) *(intx4*)&Vl[vrow + 64 * p][vcol] = vpre[p];
    __syncthreads();  // staged tile visible
    if (t + 1 < 32) {  // prefetch t+1: latency hidden under full compute phase
      const int k0n = k_base + (t + 1) * 32;
      const _Float16* g = Kb + (size_t)k0n * CC;
      kpre[0] = *(const intx4*)(g + (size_t)krow * CC + kcol);
      kpre[1] = *(const intx4*)(g + (size_t)krow * CC + kcol + 8);
      kpre[2] = *(const intx4*)(g + (size_t)(krow + 16) * CC + kcol);
      kpre[3] = *(const intx4*)(g + (size_t)(krow + 16) * CC + kcol + 8);
#pragma unroll
      for (int p = 0; p < 4; p++)
        vpre[p] = *(const intx4*)(Vb + (size_t)(vrow + 64 * p) * NN + k0n + vcol);
    }

    // S^T[k][q]: A = K rows (m=k=lane&31), B = Q frags (n=q=lane&31)
    float16v s;
#pragma unroll
    for (int i = 0; i < 16; i++) s[i] = 0.f;
#pragma unroll
    for (int cs = 0; cs < 16; cs++) {
      half8 kf = *(const half8*)&Kl[ql][cs * 16 + h * 8];
      s = __builtin_amdgcn_mfma_f32_32x32x16_f16(kf, qf[cs], s, 0, 0, 0);
    }

    // per-lane online softmax over this lane's 16 k-values (+cross-half shfl)
    float tmax = s[0];
#pragma unroll
    for (int i = 1; i < 16; i++) tmax = fmaxf(tmax, s[i]);
    tmax = fmaxf(tmax, __shfl_xor(tmax, 32));
    float mN = fmaxf(m_run, tmax);
    float alpha = __expf(m_run - mN);
    m_run = mN;
    float ts = 0.f;
#pragma unroll
    for (int i = 0; i < 16; i++) {
      float p = __expf(s[i] - mN);
      s[i] = p;
      ts += p;
    }
    ts += __shfl_xor(ts, 32);
    l_run = l_run * alpha + ts;
    if (__any(alpha != 1.0f)) {
#pragma unroll
      for (int g = 0; g < 8; g++)
#pragma unroll
        for (int i = 0; i < 16; i++) Oa[g][i] *= alpha;
    }

    // P^T -> Pl[wave][q][k] (wave-private, no block barrier)
#pragma unroll
    for (int r = 0; r < 16; r += 2) {
      half2v pk;
      pk[0] = (_Float16)s[r];
      pk[1] = (_Float16)s[r + 1];
      int kk = (r & 3) + 8 * (r >> 2) + 4 * h;  // C/D row mapping (m74/m101)
      *(half2v*)&Pl[wave][ql][kk] = pk;
    }

    // O^T += V^T-frag x P^T-frag : A = Vl rows (m=c), B = Pl rows (n=q)
#pragma unroll
    for (int ks = 0; ks < 2; ks++) {
      half8 pf = *(const half8*)&Pl[wave][ql][ks * 16 + h * 8];
#pragma unroll
      for (int g = 0; g < 8; g++) {
        half8 vf = *(const half8*)&Vl[g * 32 + ql][ks * 16 + h * 8];
        Oa[g] = __builtin_amdgcn_mfma_f32_32x32x16_f16(vf, pf, Oa[g], 0, 0, 0);
      }
    }
  }

  // epilogue: store raw fp16 partials [chunk][b][q][c] via per-wave LDS transpose
  _Float16* Opb = (ck < 2 ? Op01 : Op23) + ((size_t)(ck & 1) * NB + b) * NN * CC;
  const int qr = lane >> 1;             // 0..31
  const int chalf = (lane & 1) * 16;    // 0 or 16 channels within cgroup
#pragma unroll
  for (int g = 0; g < 8; g++) {
#pragma unroll
    for (int r = 0; r < 16; r++)
      Ot[wave][(r & 3) + 8 * (r >> 2) + 4 * h][ql] = Oa[g][r];
    __builtin_amdgcn_s_waitcnt(0);  // lgkm drain (wave-synchronous LDS)
    half8 o0, o1;
#pragma unroll
    for (int i = 0; i < 8; i++) o0[i] = (_Float16)Ot[wave][chalf + i][qr];
#pragma unroll
    for (int i = 0; i < 8; i++) o1[i] = (_Float16)Ot[wave][chalf + 8 + i][qr];
    _Float16* gp = Opb + (size_t)(q0 + qr) * CC + g * 32 + chalf;
    *(half8*)gp = o0;
    *(half8*)(gp + 8) = o1;
  }
  if (h == 0) {
    float2 ml; ml.x = m_run; ml.y = l_run;
    Ml[((size_t)ck * NB + b) * NN + q0 + ql] = ml;
  }
}

// ---------------------------------------------------------------------------
// Merge 4 split-K chunks: O = (sum_i w_i O_i) / (sum_i w_i l_i), w_i=exp(m_i-M)
// grid (64, 4b), 256 threads; thread = (q = bx*64 + t>>2, c-quarter = t&3)
// ---------------------------------------------------------------------------
__global__ __launch_bounds__(256) void k_merge(const _Float16* __restrict__ Op01,
                                               const _Float16* __restrict__ Op23,
                                               const float2* __restrict__ Ml,
                                               _Float16* __restrict__ Om) {
  const int b = blockIdx.y, t = threadIdx.x;
  const int q = blockIdx.x * 64 + (t >> 2);
  const int c0 = (t & 3) * 64;
  const size_t qi = (size_t)b * NN + q;
  float2 m0 = Ml[qi], m1 = Ml[(size_t)NB * NN + qi];
  float2 m2 = Ml[(size_t)2 * NB * NN + qi], m3 = Ml[(size_t)3 * NB * NN + qi];
  float M = fmaxf(fmaxf(m0.x, m1.x), fmaxf(m2.x, m3.x));
  float w0 = __expf(m0.x - M), w1 = __expf(m1.x - M);
  float w2 = __expf(m2.x - M), w3 = __expf(m3.x - M);
  float invL = 1.f / (w0 * m0.y + w1 * m1.y + w2 * m2.y + w3 * m3.y);
  w0 *= invL; w1 *= invL; w2 *= invL; w3 *= invL;
  const size_t off = qi * CC + c0;
  const _Float16* p0 = Op01 + off;
  const _Float16* p1 = Op01 + (size_t)NB * NN * CC + off;
  const _Float16* p2 = Op23 + off;
  const _Float16* p3 = Op23 + (size_t)NB * NN * CC + off;
  _Float16* o = Om + off;
#pragma unroll
  for (int u = 0; u < 8; u++) {
    half8 a0 = *(const half8*)(p0 + u * 8);
    half8 a1 = *(const half8*)(p1 + u * 8);
    half8 a2 = *(const half8*)(p2 + u * 8);
    half8 a3 = *(const half8*)(p3 + u * 8);
    half8 r;
#pragma unroll
    for (int i = 0; i < 8; i++)
      r[i] = (_Float16)(w0 * (float)a0[i] + w1 * (float)a1[i] +
                        w2 * (float)a2[i] + w3 * (float)a3[i]);
    *(half8*)(o + u * 8) = r;
  }
}

// ---------------------------------------------------------------------------
extern "C" void kernel_launch(void* const* d_in, const int* in_sizes, int n_in,
                              void* d_out, int out_size, void* d_ws, size_t ws_size,
                              hipStream_t stream) {
  const float* Fc = (const float*)d_in[0];
  const float* Fs = (const float*)d_in[1];
  const float* Wf = (const float*)d_in[2];
  const float* bf_ = (const float*)d_in[3];
  const float* Wg = (const float*)d_in[4];
  const float* bg = (const float*)d_in[5];
  const float* Wh = (const float*)d_in[6];
  const float* bh = (const float*)d_in[7];
  const float* Wo = (const float*)d_in[8];
  const float* bo = (const float*)d_in[9];

  char* ws = (char*)d_ws;
  const size_t sz = (size_t)NB * NN * CC * sizeof(_Float16);  // 8 MB per plane
  _Float16* Xct = (_Float16*)(ws + 0 * sz);
  _Float16* Xst = (_Float16*)(ws + 1 * sz);
  _Float16* Qf  = (_Float16*)(ws + 2 * sz);
  _Float16* Kf  = (_Float16*)(ws + 3 * sz);
  _Float16* Vtf = (_Float16*)(ws + 4 * sz);
  _Float16* Om  = (_Float16*)(ws + 5 * sz);
  _Float16* Op23 = (_Float16*)(ws + 6 * sz);       // chunks 2,3 (16 MB)
  _Float16* Op01 = Xct;                             // chunks 0,1 overlay Xct+Xst (dead by attn)
  _Float16* Wf16 = (_Float16*)(ws + 8 * sz);
  _Float16* Wg16 = Wf16 + 65536;
  _Float16* Wh16 = Wg16 + 65536;
  _Float16* Wo16 = Wh16 + 65536;
  float2* Ml = (float2*)(Wo16 + 65536);             // 4*4*4096 float2 = 512 KB

  const long bs = (long)NN * CC;  // per-batch stride (elements)

  k_transpose<<<dim3(64, 4, 8), 256, 0, stream>>>(Fc, Fs, Xct, Xst);
  k_wconv<<<dim3(256), 256, 0, stream>>>(Wf, Wg, Wh, Wo, Wf16, Wg16, Wh16, Wo16);
  // Q[n][d] = Wf . Xct^T : A=Wf (2 Mtiles), B=Xct (32 Ntiles)
  k_proj<0><<<dim3(64, NB), 256, 0, stream>>>(Wf16, 0, Xct, bs, bf_, Qf, bs, 32);
  // K[n][d]
  k_proj<0><<<dim3(64, NB), 256, 0, stream>>>(Wg16, 0, Xst, bs, bg, Kf, bs, 32);
  // Vt[d][n]: A=Xst (32 Mtiles), B=Wh (2 Ntiles)
  k_proj<1><<<dim3(64, NB), 256, 0, stream>>>(Xst, bs, Wh16, 0, bh, Vtf, bs, 2);
  // attention partials (split-K x4)
  k_attn<<<dim3(32, 4, NB), 256, 0, stream>>>(Qf, Kf, Vtf, Op01, Op23, Ml);
  // merge chunks -> Om [b][n][c]
  k_merge<<<dim3(64, NB), 256, 0, stream>>>(Op01, Op23, Ml, Om);
  // final conv: out[d][n] f32 = Wo . Om^T + bo
  k_proj<2><<<dim3(64, NB), 256, 0, stream>>>(Om, bs, Wo16, 0, bo, d_out, bs, 2);
}

// Round 5
// 226.866 us; speedup vs baseline: 2.8600x; 1.1303x over previous
//
#include <hip/hip_runtime.h>
#include <stdint.h>

#define NB 4
#define CC 256
#define NN 4096   // H*W = 64*64
#define KITERS 32 // k-steps per attention chunk (chunk = 1024)

typedef __attribute__((ext_vector_type(8))) _Float16 half8;   // MFMA A/B frag (4 VGPR)
typedef __attribute__((ext_vector_type(4))) _Float16 half4;   // 8B packed store
typedef __attribute__((ext_vector_type(2))) _Float16 half2v;
typedef __attribute__((ext_vector_type(4))) float floatx4;    // 16x16 acc
typedef __attribute__((ext_vector_type(16))) float float16v;  // 32x32 acc
typedef __attribute__((ext_vector_type(4))) int intx4;        // 16B copy

__device__ __forceinline__ void cvt16(const float4* src, half8& lo, half8& hi) {
  float4 a = src[0], b = src[1], c = src[2], d = src[3];
  lo[0] = (_Float16)a.x; lo[1] = (_Float16)a.y; lo[2] = (_Float16)a.z; lo[3] = (_Float16)a.w;
  lo[4] = (_Float16)b.x; lo[5] = (_Float16)b.y; lo[6] = (_Float16)b.z; lo[7] = (_Float16)b.w;
  hi[0] = (_Float16)c.x; hi[1] = (_Float16)c.y; hi[2] = (_Float16)c.z; hi[3] = (_Float16)c.w;
  hi[4] = (_Float16)d.x; hi[5] = (_Float16)d.y; hi[6] = (_Float16)d.z; hi[7] = (_Float16)d.w;
}

// ---------------------------------------------------------------------------
// Transpose + fp32->fp16: F [b][c][n] f32 -> Xt [b][n][c] f16
// grid (64 n-tiles, 4 c-tiles, 8 = b*2+which), 256 threads
// ---------------------------------------------------------------------------
__global__ __launch_bounds__(256) void k_transpose(const float* __restrict__ Fc,
                                                   const float* __restrict__ Fs,
                                                   _Float16* __restrict__ Xct,
                                                   _Float16* __restrict__ Xst) {
  __shared__ float t[64][65];
  const int nt = blockIdx.x, ct = blockIdx.y, bz = blockIdx.z;
  const int b = bz >> 1;
  const float* src = ((bz & 1) ? Fs : Fc) + (size_t)b * CC * NN;
  _Float16* dst = ((bz & 1) ? Xst : Xct) + (size_t)b * NN * CC;
  const int tid = threadIdx.x;
  const int n0 = nt * 64, c0 = ct * 64;
  const int col = tid & 63, row4 = tid >> 6;
#pragma unroll
  for (int i = 0; i < 16; i++) {
    int c = row4 + i * 4;
    t[c][col] = src[(size_t)(c0 + c) * NN + n0 + col];  // coalesced over n
  }
  __syncthreads();
#pragma unroll
  for (int i = 0; i < 16; i++) {
    int n = row4 + i * 4;
    dst[(size_t)(n0 + n) * CC + c0 + col] = (_Float16)t[col][n];  // coalesced over c
  }
}

// ---------------------------------------------------------------------------
// Fused Q/K/V projection GEMMs, one launch. grid (64, NB, 3), 256 threads.
// z=0: Q[n][d] = Wf.Xct^T   z=1: K[n][d] = Wg.Xst^T   z=2: Vt[d][n] = (Xst.Wh^T)^T
// Weights are fp32 and converted to fp16 inline during LDS staging.
// ---------------------------------------------------------------------------
__global__ __launch_bounds__(256, 2) void k_qkv(const float* __restrict__ Wf,
                                                const float* __restrict__ Wg,
                                                const float* __restrict__ Wh,
                                                const _Float16* __restrict__ Xct,
                                                const _Float16* __restrict__ Xst,
                                                const float* __restrict__ bf,
                                                const float* __restrict__ bg,
                                                const float* __restrict__ bh,
                                                _Float16* __restrict__ Qf,
                                                _Float16* __restrict__ Kf,
                                                _Float16* __restrict__ Vtf) {
  __shared__ _Float16 As[128][40];  // 80B rows
  __shared__ _Float16 Bs[128][40];
  const int z = blockIdx.z, bz = blockIdx.y;
  const float* W = (z == 0) ? Wf : ((z == 1) ? Wg : Wh);
  const _Float16* X = ((z == 0) ? Xct : Xst) + (size_t)bz * NN * CC;
  const float* bias = (z == 0) ? bf : ((z == 1) ? bg : bh);
  int mt, nt;
  if (z < 2) { mt = blockIdx.x >> 5; nt = blockIdx.x & 31; }  // M=d(256), N=n(4096)
  else       { mt = blockIdx.x >> 1; nt = blockIdx.x & 1;  }  // M=n(4096), N=d(256)
  const int m0 = mt * 128, n0 = nt * 128;
  const int tid = threadIdx.x;
  const int wave = tid >> 6, lane = tid & 63, quad = lane >> 4, l15 = lane & 15;
  const int wm = (wave >> 1) * 64, wn = (wave & 1) * 64;

  floatx4 acc[4][4];
#pragma unroll
  for (int i = 0; i < 4; i++)
#pragma unroll
    for (int j = 0; j < 4; j++) acc[i][j] = (floatx4){0.f, 0.f, 0.f, 0.f};

  const int srow = tid >> 1;
  const int shalf = (tid & 1) * 16;

  for (int kk = 0; kk < 256; kk += 32) {
    half8 a_lo, a_hi, b_lo, b_hi;
    if (z < 2) {
      cvt16((const float4*)(W + (size_t)(m0 + srow) * 256 + kk + shalf), a_lo, a_hi);
      const _Float16* bp = X + (size_t)(n0 + srow) * 256 + kk + shalf;
      b_lo = *(const half8*)bp; b_hi = *(const half8*)(bp + 8);
    } else {
      const _Float16* ap = X + (size_t)(m0 + srow) * 256 + kk + shalf;
      a_lo = *(const half8*)ap; a_hi = *(const half8*)(ap + 8);
      cvt16((const float4*)(W + (size_t)(n0 + srow) * 256 + kk + shalf), b_lo, b_hi);
    }
    __syncthreads();
    *(half8*)&As[srow][shalf] = a_lo;
    *(half8*)&As[srow][shalf + 8] = a_hi;
    *(half8*)&Bs[srow][shalf] = b_lo;
    *(half8*)&Bs[srow][shalf + 8] = b_hi;
    __syncthreads();
    half8 af[4], bfr[4];
#pragma unroll
    for (int mb = 0; mb < 4; mb++) af[mb] = *(const half8*)&As[wm + mb * 16 + l15][quad * 8];
#pragma unroll
    for (int nb = 0; nb < 4; nb++) bfr[nb] = *(const half8*)&Bs[wn + nb * 16 + l15][quad * 8];
#pragma unroll
    for (int mb = 0; mb < 4; mb++)
#pragma unroll
      for (int nb = 0; nb < 4; nb++)
        acc[mb][nb] = __builtin_amdgcn_mfma_f32_16x16x32_f16(af[mb], bfr[nb], acc[mb][nb], 0, 0, 0);
  }

  if (z < 2) {
    _Float16* op = (z == 0 ? Qf : Kf) + (size_t)bz * NN * CC;
#pragma unroll
    for (int mb = 0; mb < 4; mb++) {
      int d0 = m0 + wm + mb * 16 + quad * 4;
      float b0 = bias[d0], b1 = bias[d0 + 1], b2 = bias[d0 + 2], b3 = bias[d0 + 3];
#pragma unroll
      for (int nb = 0; nb < 4; nb++) {
        int n_ = n0 + wn + nb * 16 + l15;
        half4 pk;
        pk[0] = (_Float16)(acc[mb][nb][0] + b0);
        pk[1] = (_Float16)(acc[mb][nb][1] + b1);
        pk[2] = (_Float16)(acc[mb][nb][2] + b2);
        pk[3] = (_Float16)(acc[mb][nb][3] + b3);
        *(half4*)(op + (size_t)n_ * CC + d0) = pk;
      }
    }
  } else {
    _Float16* op = Vtf + (size_t)bz * NN * CC;
#pragma unroll
    for (int mb = 0; mb < 4; mb++) {
      int nq0 = m0 + wm + mb * 16 + quad * 4;  // spatial
#pragma unroll
      for (int nb = 0; nb < 4; nb++) {
        int d = n0 + wn + nb * 16 + l15;
        float bv = bias[d];
        half4 pk;
        pk[0] = (_Float16)(acc[mb][nb][0] + bv);
        pk[1] = (_Float16)(acc[mb][nb][1] + bv);
        pk[2] = (_Float16)(acc[mb][nb][2] + bv);
        pk[3] = (_Float16)(acc[mb][nb][3] + bv);
        *(half4*)(op + (size_t)d * NN + nq0) = pk;
      }
    }
  }
}

// ---------------------------------------------------------------------------
// Flash attention v5 (fp16, unscaled logits), split-K x4, software-pipelined.
// Per iter t: stage K(t),V(t) -> [MFMA burst: S(t) interleaved with PV(t-1)]
// -> lazy online-softmax -> P(t). Vl double-buffered; Pl single (wave-local,
// in-order LDS). Partials stored NORMALIZED (O/l); Ml=(m,l) per q.
// grid (32 qtiles, 4 chunks, NB), 256 threads, 2 barriers/iter.
// ---------------------------------------------------------------------------
__global__ __launch_bounds__(256, 2) void k_attn(const _Float16* __restrict__ Q,
                                                 const _Float16* __restrict__ K,
                                                 const _Float16* __restrict__ Vt,
                                                 _Float16* __restrict__ Opart,
                                                 float2* __restrict__ Ml) {
  __shared__ _Float16 Kl[32][264];      // 16.9 KB (reused as epilogue f32 scratch)
  __shared__ _Float16 Vl[2][256][40];   // 2 x 20.5 KB
  __shared__ _Float16 Pl[4][32][40];    // 10.2 KB per-wave P scratch

  const int qt = blockIdx.x, ck = blockIdx.y, b = blockIdx.z;
  const int tid = threadIdx.x;
  const int wave = tid >> 6, lane = tid & 63;
  const int ql = lane & 31, h = lane >> 5;
  const int q0 = qt * 128 + wave * 32;
  const _Float16* Qb = Q + (size_t)b * NN * CC;
  const _Float16* Kb = K + (size_t)b * NN * CC;
  const _Float16* Vb = Vt + (size_t)b * CC * NN;
  const int k_base = ck * 1024;

  // Q B-frags in registers: B[n=q=lane&31][c], 16 c-steps
  half8 qf[16];
#pragma unroll
  for (int cs = 0; cs < 16; cs++)
    qf[cs] = *(const half8*)(Qb + (size_t)(q0 + ql) * CC + cs * 16 + h * 8);

  float16v Oa[8];  // O^T acc: [cgroup] D[m=c][n=q]
#pragma unroll
  for (int g = 0; g < 8; g++)
#pragma unroll
    for (int i = 0; i < 16; i++) Oa[g][i] = 0.f;

  float m_run = -1e30f, l_run = 0.f;

  const int krow = tid >> 4;          // 0..15 (+16 second pass)
  const int kcol = (tid & 15) * 16;   // halves
  const int vrow = tid >> 2;          // 0..63 (+64p)
  const int vcol = (tid & 3) * 8;     // halves

  intx4 kpre[4], vpre[4];
  {
    const _Float16* g = Kb + (size_t)k_base * CC;
    kpre[0] = *(const intx4*)(g + (size_t)krow * CC + kcol);
    kpre[1] = *(const intx4*)(g + (size_t)krow * CC + kcol + 8);
    kpre[2] = *(const intx4*)(g + (size_t)(krow + 16) * CC + kcol);
    kpre[3] = *(const intx4*)(g + (size_t)(krow + 16) * CC + kcol + 8);
#pragma unroll
    for (int p = 0; p < 4; p++)
      vpre[p] = *(const intx4*)(Vb + (size_t)(vrow + 64 * p) * NN + k_base + vcol);
  }

  for (int t = 0; t < KITERS; t++) {
    const int vb = t & 1;
    __syncthreads();  // A: all waves done with Kl(t-1), Vl[vb](t-2)
    *(intx4*)&Kl[krow][kcol] = kpre[0];
    *(intx4*)&Kl[krow][kcol + 8] = kpre[1];
    *(intx4*)&Kl[krow + 16][kcol] = kpre[2];
    *(intx4*)&Kl[krow + 16][kcol + 8] = kpre[3];
#pragma unroll
    for (int p = 0; p < 4; p++) *(intx4*)&Vl[vb][vrow + 64 * p][vcol] = vpre[p];
    __syncthreads();  // B: tile t visible
    if (t + 1 < KITERS) {  // prefetch t+1 (latency hidden under burst+softmax)
      const int k0n = k_base + (t + 1) * 32;
      const _Float16* g = Kb + (size_t)k0n * CC;
      kpre[0] = *(const intx4*)(g + (size_t)krow * CC + kcol);
      kpre[1] = *(const intx4*)(g + (size_t)krow * CC + kcol + 8);
      kpre[2] = *(const intx4*)(g + (size_t)(krow + 16) * CC + kcol);
      kpre[3] = *(const intx4*)(g + (size_t)(krow + 16) * CC + kcol + 8);
#pragma unroll
      for (int p = 0; p < 4; p++)
        vpre[p] = *(const intx4*)(Vb + (size_t)(vrow + 64 * p) * NN + k0n + vcol);
    }

    // ---- MFMA burst: S(t) interleaved with PV(t-1) (9 independent chains)
    float16v s;
#pragma unroll
    for (int i = 0; i < 16; i++) s[i] = 0.f;
    if (t > 0) {
      const int vr = vb ^ 1;  // V buffer of tile t-1
      half8 pf0 = *(const half8*)&Pl[wave][ql][h * 8];
      half8 pf1 = *(const half8*)&Pl[wave][ql][16 + h * 8];
#pragma unroll
      for (int u = 0; u < 8; u++) {
        half8 kfa = *(const half8*)&Kl[ql][(2 * u) * 16 + h * 8];
        s = __builtin_amdgcn_mfma_f32_32x32x16_f16(kfa, qf[2 * u], s, 0, 0, 0);
        half8 vfa = *(const half8*)&Vl[vr][u * 32 + ql][h * 8];
        Oa[u] = __builtin_amdgcn_mfma_f32_32x32x16_f16(vfa, pf0, Oa[u], 0, 0, 0);
        half8 kfb = *(const half8*)&Kl[ql][(2 * u + 1) * 16 + h * 8];
        s = __builtin_amdgcn_mfma_f32_32x32x16_f16(kfb, qf[2 * u + 1], s, 0, 0, 0);
        half8 vfb = *(const half8*)&Vl[vr][u * 32 + ql][16 + h * 8];
        Oa[u] = __builtin_amdgcn_mfma_f32_32x32x16_f16(vfb, pf1, Oa[u], 0, 0, 0);
      }
    } else {
#pragma unroll
      for (int cs = 0; cs < 16; cs++) {
        half8 kf = *(const half8*)&Kl[ql][cs * 16 + h * 8];
        s = __builtin_amdgcn_mfma_f32_32x32x16_f16(kf, qf[cs], s, 0, 0, 0);
      }
    }

    // ---- lazy online softmax (per-lane; q = lane&31, halves merged by shfl)
    float tmax = s[0];
#pragma unroll
    for (int i = 1; i < 16; i++) tmax = fmaxf(tmax, s[i]);
    tmax = fmaxf(tmax, __shfl_xor(tmax, 32));
    bool need = tmax > m_run + 8.0f;
    if (__any((int)need)) {
      float mN = need ? tmax : m_run;
      float alpha = __expf(m_run - mN);
      m_run = mN;
      l_run *= alpha;
#pragma unroll
      for (int g = 0; g < 8; g++)
#pragma unroll
        for (int i = 0; i < 16; i++) Oa[g][i] *= alpha;
    }
    float ts = 0.f;
#pragma unroll
    for (int i = 0; i < 16; i++) {
      float p = __expf(s[i] - m_run);
      s[i] = p;
      ts += p;
    }
    ts += __shfl_xor(ts, 32);
    l_run += ts;
    // P(t) -> Pl (wave-private; read next iter by same wave, in-order LDS)
#pragma unroll
    for (int r = 0; r < 16; r += 2) {
      half2v pk;
      pk[0] = (_Float16)s[r];
      pk[1] = (_Float16)s[r + 1];
      int kk2 = (r & 3) + 8 * (r >> 2) + 4 * h;  // C/D row mapping
      *(half2v*)&Pl[wave][ql][kk2] = pk;
    }
  }

  // ---- tail: PV for last tile
  {
    const int vr = (KITERS - 1) & 1;
    half8 pf0 = *(const half8*)&Pl[wave][ql][h * 8];
    half8 pf1 = *(const half8*)&Pl[wave][ql][16 + h * 8];
#pragma unroll
    for (int u = 0; u < 8; u++) {
      half8 vfa = *(const half8*)&Vl[vr][u * 32 + ql][h * 8];
      Oa[u] = __builtin_amdgcn_mfma_f32_32x32x16_f16(vfa, pf0, Oa[u], 0, 0, 0);
      half8 vfb = *(const half8*)&Vl[vr][u * 32 + ql][16 + h * 8];
      Oa[u] = __builtin_amdgcn_mfma_f32_32x32x16_f16(vfb, pf1, Oa[u], 0, 0, 0);
    }
  }

  // ---- epilogue: normalize by 1/l, per-wave transpose via Kl scratch, store
  float invl = 1.f / l_run;
  __syncthreads();  // all waves done reading Kl
  float* ot = (float*)(&Kl[0][0]) + wave * (32 * 33);
  _Float16* Opb = Opart + ((size_t)ck * NB + b) * NN * CC;
  const int qr = lane >> 1;
  const int chalf = (lane & 1) * 16;
#pragma unroll
  for (int g = 0; g < 8; g++) {
#pragma unroll
    for (int r = 0; r < 16; r++)
      ot[((r & 3) + 8 * (r >> 2) + 4 * h) * 33 + ql] = Oa[g][r] * invl;
    __builtin_amdgcn_s_waitcnt(0);  // wave-sync LDS
    half8 o0, o1;
#pragma unroll
    for (int i = 0; i < 8; i++) o0[i] = (_Float16)ot[(chalf + i) * 33 + qr];
#pragma unroll
    for (int i = 0; i < 8; i++) o1[i] = (_Float16)ot[(chalf + 8 + i) * 33 + qr];
    _Float16* gp = Opb + (size_t)(q0 + qr) * CC + g * 32 + chalf;
    *(half8*)gp = o0;
    *(half8*)(gp + 8) = o1;
    __builtin_amdgcn_s_waitcnt(0);  // reads done before next g overwrites ot
  }
  if (h == 0) {
    float2 ml; ml.x = m_run; ml.y = l_run;
    Ml[((size_t)ck * NB + b) * NN + q0 + ql] = ml;
  }
}

// ---------------------------------------------------------------------------
// Merge 4 normalized chunks: O = sum_i c_i O'_i, c_i = w_i l_i / sum w_j l_j,
// w_i = exp(m_i - M). grid (128, NB), 256 threads.
// ---------------------------------------------------------------------------
__global__ __launch_bounds__(256) void k_merge(const _Float16* __restrict__ Opart,
                                               const float2* __restrict__ Ml,
                                               _Float16* __restrict__ Om) {
  const int b = blockIdx.y, t = threadIdx.x;
  const int q = blockIdx.x * 32 + (t >> 3);
  const int c0 = (t & 7) * 32;
  const size_t qi = (size_t)b * NN + q;
  float2 m0 = Ml[qi], m1 = Ml[(size_t)NB * NN + qi];
  float2 m2 = Ml[(size_t)2 * NB * NN + qi], m3 = Ml[(size_t)3 * NB * NN + qi];
  float M = fmaxf(fmaxf(m0.x, m1.x), fmaxf(m2.x, m3.x));
  float w0 = __expf(m0.x - M) * m0.y, w1 = __expf(m1.x - M) * m1.y;
  float w2 = __expf(m2.x - M) * m2.y, w3 = __expf(m3.x - M) * m3.y;
  float inv = 1.f / (w0 + w1 + w2 + w3);
  w0 *= inv; w1 *= inv; w2 *= inv; w3 *= inv;
  const size_t off = qi * CC + c0;
  const size_t ps = (size_t)NB * NN * CC;
  const _Float16* p0 = Opart + off;
  const _Float16* p1 = Opart + ps + off;
  const _Float16* p2 = Opart + 2 * ps + off;
  const _Float16* p3 = Opart + 3 * ps + off;
  _Float16* o = Om + off;
#pragma unroll
  for (int u = 0; u < 4; u++) {
    half8 a0 = *(const half8*)(p0 + u * 8);
    half8 a1 = *(const half8*)(p1 + u * 8);
    half8 a2 = *(const half8*)(p2 + u * 8);
    half8 a3 = *(const half8*)(p3 + u * 8);
    half8 r;
#pragma unroll
    for (int i = 0; i < 8; i++)
      r[i] = (_Float16)(w0 * (float)a0[i] + w1 * (float)a1[i] +
                        w2 * (float)a2[i] + w3 * (float)a3[i]);
    *(half8*)(o + u * 8) = r;
  }
}

// ---------------------------------------------------------------------------
// Final conv: out[b][d][n] fp32 = Wo . Om^T + bo. A = Om fp16 (M=spatial),
// B = Wo fp32 inline-cvt. grid (64, NB), 256 threads.
// ---------------------------------------------------------------------------
__global__ __launch_bounds__(256, 2) void k_out(const _Float16* __restrict__ Om,
                                                const float* __restrict__ Wo,
                                                const float* __restrict__ bo,
                                                float* __restrict__ out) {
  __shared__ _Float16 As[128][40];
  __shared__ _Float16 Bs[128][40];
  const int bz = blockIdx.y;
  const int mt = blockIdx.x >> 1, nt = blockIdx.x & 1;
  const int m0 = mt * 128, n0 = nt * 128;
  const int tid = threadIdx.x;
  const int wave = tid >> 6, lane = tid & 63, quad = lane >> 4, l15 = lane & 15;
  const int wm = (wave >> 1) * 64, wn = (wave & 1) * 64;
  const _Float16* X = Om + (size_t)bz * NN * CC;

  floatx4 acc[4][4];
#pragma unroll
  for (int i = 0; i < 4; i++)
#pragma unroll
    for (int j = 0; j < 4; j++) acc[i][j] = (floatx4){0.f, 0.f, 0.f, 0.f};

  const int srow = tid >> 1;
  const int shalf = (tid & 1) * 16;

  for (int kk = 0; kk < 256; kk += 32) {
    const _Float16* ap = X + (size_t)(m0 + srow) * 256 + kk + shalf;
    half8 a_lo = *(const half8*)ap;
    half8 a_hi = *(const half8*)(ap + 8);
    half8 b_lo, b_hi;
    cvt16((const float4*)(Wo + (size_t)(n0 + srow) * 256 + kk + shalf), b_lo, b_hi);
    __syncthreads();
    *(half8*)&As[srow][shalf] = a_lo;
    *(half8*)&As[srow][shalf + 8] = a_hi;
    *(half8*)&Bs[srow][shalf] = b_lo;
    *(half8*)&Bs[srow][shalf + 8] = b_hi;
    __syncthreads();
    half8 af[4], bfr[4];
#pragma unroll
    for (int mb = 0; mb < 4; mb++) af[mb] = *(const half8*)&As[wm + mb * 16 + l15][quad * 8];
#pragma unroll
    for (int nb = 0; nb < 4; nb++) bfr[nb] = *(const half8*)&Bs[wn + nb * 16 + l15][quad * 8];
#pragma unroll
    for (int mb = 0; mb < 4; mb++)
#pragma unroll
      for (int nb = 0; nb < 4; nb++)
        acc[mb][nb] = __builtin_amdgcn_mfma_f32_16x16x32_f16(af[mb], bfr[nb], acc[mb][nb], 0, 0, 0);
  }

  float* op = out + (size_t)bz * NN * CC;
#pragma unroll
  for (int mb = 0; mb < 4; mb++) {
    int nq0 = m0 + wm + mb * 16 + quad * 4;  // spatial
#pragma unroll
    for (int nb = 0; nb < 4; nb++) {
      int d = n0 + wn + nb * 16 + l15;
      float bv = bo[d];
      floatx4 pk;
      pk[0] = acc[mb][nb][0] + bv;
      pk[1] = acc[mb][nb][1] + bv;
      pk[2] = acc[mb][nb][2] + bv;
      pk[3] = acc[mb][nb][3] + bv;
      *(floatx4*)(op + (size_t)d * NN + nq0) = pk;  // 16B
    }
  }
}

// ---------------------------------------------------------------------------
extern "C" void kernel_launch(void* const* d_in, const int* in_sizes, int n_in,
                              void* d_out, int out_size, void* d_ws, size_t ws_size,
                              hipStream_t stream) {
  const float* Fc = (const float*)d_in[0];
  const float* Fs = (const float*)d_in[1];
  const float* Wf = (const float*)d_in[2];
  const float* bf_ = (const float*)d_in[3];
  const float* Wg = (const float*)d_in[4];
  const float* bg = (const float*)d_in[5];
  const float* Wh = (const float*)d_in[6];
  const float* bh = (const float*)d_in[7];
  const float* Wo = (const float*)d_in[8];
  const float* bo = (const float*)d_in[9];

  char* ws = (char*)d_ws;
  const size_t sz = (size_t)NB * NN * CC * sizeof(_Float16);  // 8 MB per plane
  // plane layout (7 planes + Ml = 56.5 MB):
  _Float16* Xct = (_Float16*)(ws + 0 * sz);   // -> attn partial ck0
  _Float16* Xst = (_Float16*)(ws + 1 * sz);   // -> attn partial ck1
  _Float16* Opart = Xct;                      // partials ck0..ck3 = planes 0..3
  _Float16* Qf  = (_Float16*)(ws + 4 * sz);   // -> Om after merge (Qf dead)
  _Float16* Kf  = (_Float16*)(ws + 5 * sz);
  _Float16* Vtf = (_Float16*)(ws + 6 * sz);
  _Float16* Om  = Qf;
  float2* Ml = (float2*)(ws + 7 * sz);        // 4*4*4096 float2 = 512 KB

  k_transpose<<<dim3(64, 4, 8), 256, 0, stream>>>(Fc, Fs, Xct, Xst);
  k_qkv<<<dim3(64, NB, 3), 256, 0, stream>>>(Wf, Wg, Wh, Xct, Xst, bf_, bg, bh, Qf, Kf, Vtf);
  k_attn<<<dim3(32, 4, NB), 256, 0, stream>>>(Qf, Kf, Vtf, Opart, Ml);
  k_merge<<<dim3(128, NB), 256, 0, stream>>>(Opart, Ml, Om);
  k_out<<<dim3(64, NB), 256, 0, stream>>>(Om, Wo, bo, (float*)d_out);
}

// Round 7
// 216.531 us; speedup vs baseline: 2.9965x; 1.0477x over previous
//
#include <hip/hip_runtime.h>
#include <stdint.h>

#define NB 4
#define CC 256
#define NN 4096   // H*W = 64*64
#define KITERS 32 // k-steps per attention chunk (chunk = 1024)
#define WAIT_LGKM0 0xC07F  // s_waitcnt lgkmcnt(0), vmcnt/expcnt untouched

typedef __attribute__((ext_vector_type(8))) _Float16 half8;   // MFMA A/B frag (4 VGPR)
typedef __attribute__((ext_vector_type(4))) _Float16 half4;   // 8B packed store
typedef __attribute__((ext_vector_type(2))) _Float16 half2v;
typedef __attribute__((ext_vector_type(4))) float floatx4;    // 16x16 acc
typedef __attribute__((ext_vector_type(16))) float float16v;  // 32x32 acc
typedef __attribute__((ext_vector_type(4))) int intx4;        // 16B copy

__device__ __forceinline__ void cvt16(const float4* src, half8& lo, half8& hi) {
  float4 a = src[0], b = src[1], c = src[2], d = src[3];
  lo[0] = (_Float16)a.x; lo[1] = (_Float16)a.y; lo[2] = (_Float16)a.z; lo[3] = (_Float16)a.w;
  lo[4] = (_Float16)b.x; lo[5] = (_Float16)b.y; lo[6] = (_Float16)b.z; lo[7] = (_Float16)b.w;
  hi[0] = (_Float16)c.x; hi[1] = (_Float16)c.y; hi[2] = (_Float16)c.z; hi[3] = (_Float16)c.w;
  hi[4] = (_Float16)d.x; hi[5] = (_Float16)d.y; hi[6] = (_Float16)d.z; hi[7] = (_Float16)d.w;
}

// ---------------------------------------------------------------------------
// Transpose + fp32->fp16: F [b][c][n] f32 -> Xt [b][n][c] f16
// ---------------------------------------------------------------------------
__global__ __launch_bounds__(256) void k_transpose(const float* __restrict__ Fc,
                                                   const float* __restrict__ Fs,
                                                   _Float16* __restrict__ Xct,
                                                   _Float16* __restrict__ Xst) {
  __shared__ float t[64][65];
  const int nt = blockIdx.x, ct = blockIdx.y, bz = blockIdx.z;
  const int b = bz >> 1;
  const float* src = ((bz & 1) ? Fs : Fc) + (size_t)b * CC * NN;
  _Float16* dst = ((bz & 1) ? Xst : Xct) + (size_t)b * NN * CC;
  const int tid = threadIdx.x;
  const int n0 = nt * 64, c0 = ct * 64;
  const int col = tid & 63, row4 = tid >> 6;
#pragma unroll
  for (int i = 0; i < 16; i++) {
    int c = row4 + i * 4;
    t[c][col] = src[(size_t)(c0 + c) * NN + n0 + col];
  }
  __syncthreads();
#pragma unroll
  for (int i = 0; i < 16; i++) {
    int n = row4 + i * 4;
    dst[(size_t)(n0 + n) * CC + c0 + col] = (_Float16)t[col][n];
  }
}

// ---------------------------------------------------------------------------
// Fused Q/K/V projections -> FRAG-MAJOR (swizzled) outputs for k_attn.
// Q/K swizzle: idx = ((kt*16 + cs)*64 + ql + 32*hh)*8 + j   (kt=n>>5, ql=n&31,
//   cs=d>>4, hh=(d>>3)&1, j=d&7)
// V swizzle:  idx = (((kt*8 + g)*2 + hk)*64 + ql + 32*hh)*8 + j  (kt=n>>5 spatial,
//   hk=(n>>4)&1, hh=(n>>3)&1, j=n&7, g=d>>5, ql=d&31)
// grid (64, NB, 3), 256 threads.
// ---------------------------------------------------------------------------
__global__ __launch_bounds__(256, 2) void k_qkv(const float* __restrict__ Wf,
                                                const float* __restrict__ Wg,
                                                const float* __restrict__ Wh,
                                                const _Float16* __restrict__ Xct,
                                                const _Float16* __restrict__ Xst,
                                                const float* __restrict__ bf,
                                                const float* __restrict__ bg,
                                                const float* __restrict__ bh,
                                                _Float16* __restrict__ Qs,
                                                _Float16* __restrict__ Ks,
                                                _Float16* __restrict__ Vs) {
  __shared__ _Float16 As[128][40];
  __shared__ _Float16 Bs[128][40];
  const int z = blockIdx.z, bz = blockIdx.y;
  const float* W = (z == 0) ? Wf : ((z == 1) ? Wg : Wh);
  const _Float16* X = ((z == 0) ? Xct : Xst) + (size_t)bz * NN * CC;
  const float* bias = (z == 0) ? bf : ((z == 1) ? bg : bh);
  int mt, nt;
  if (z < 2) { mt = blockIdx.x >> 5; nt = blockIdx.x & 31; }  // M=d(256), N=n(4096)
  else       { mt = blockIdx.x >> 1; nt = blockIdx.x & 1;  }  // M=n(4096), N=d(256)
  const int m0 = mt * 128, n0 = nt * 128;
  const int tid = threadIdx.x;
  const int wave = tid >> 6, lane = tid & 63, quad = lane >> 4, l15 = lane & 15;
  const int wm = (wave >> 1) * 64, wn = (wave & 1) * 64;

  floatx4 acc[4][4];
#pragma unroll
  for (int i = 0; i < 4; i++)
#pragma unroll
    for (int j = 0; j < 4; j++) acc[i][j] = (floatx4){0.f, 0.f, 0.f, 0.f};

  const int srow = tid >> 1;
  const int shalf = (tid & 1) * 16;

  for (int kk = 0; kk < 256; kk += 32) {
    half8 a_lo, a_hi, b_lo, b_hi;
    if (z < 2) {
      cvt16((const float4*)(W + (size_t)(m0 + srow) * 256 + kk + shalf), a_lo, a_hi);
      const _Float16* bp = X + (size_t)(n0 + srow) * 256 + kk + shalf;
      b_lo = *(const half8*)bp; b_hi = *(const half8*)(bp + 8);
    } else {
      const _Float16* ap = X + (size_t)(m0 + srow) * 256 + kk + shalf;
      a_lo = *(const half8*)ap; a_hi = *(const half8*)(ap + 8);
      cvt16((const float4*)(W + (size_t)(n0 + srow) * 256 + kk + shalf), b_lo, b_hi);
    }
    __syncthreads();
    *(half8*)&As[srow][shalf] = a_lo;
    *(half8*)&As[srow][shalf + 8] = a_hi;
    *(half8*)&Bs[srow][shalf] = b_lo;
    *(half8*)&Bs[srow][shalf + 8] = b_hi;
    __syncthreads();
    half8 af[4], bfr[4];
#pragma unroll
    for (int mb = 0; mb < 4; mb++) af[mb] = *(const half8*)&As[wm + mb * 16 + l15][quad * 8];
#pragma unroll
    for (int nb = 0; nb < 4; nb++) bfr[nb] = *(const half8*)&Bs[wn + nb * 16 + l15][quad * 8];
#pragma unroll
    for (int mb = 0; mb < 4; mb++)
#pragma unroll
      for (int nb = 0; nb < 4; nb++)
        acc[mb][nb] = __builtin_amdgcn_mfma_f32_16x16x32_f16(af[mb], bfr[nb], acc[mb][nb], 0, 0, 0);
  }

  if (z < 2) {
    _Float16* op = (z == 0 ? Qs : Ks) + (size_t)bz * NN * CC;
#pragma unroll
    for (int mb = 0; mb < 4; mb++) {
      int d0 = m0 + wm + mb * 16 + quad * 4;  // channel, mult of 4
      float b0 = bias[d0], b1 = bias[d0 + 1], b2 = bias[d0 + 2], b3 = bias[d0 + 3];
      const int cs = d0 >> 4, hh = (d0 >> 3) & 1, j0 = d0 & 7;
#pragma unroll
      for (int nb = 0; nb < 4; nb++) {
        int n_ = n0 + wn + nb * 16 + l15;  // spatial
        int kt = n_ >> 5, ql_ = n_ & 31;
        half4 pk;
        pk[0] = (_Float16)(acc[mb][nb][0] + b0);
        pk[1] = (_Float16)(acc[mb][nb][1] + b1);
        pk[2] = (_Float16)(acc[mb][nb][2] + b2);
        pk[3] = (_Float16)(acc[mb][nb][3] + b3);
        size_t idx = ((size_t)(kt * 16 + cs) * 64 + ql_ + 32 * hh) * 8 + j0;
        *(half4*)(op + idx) = pk;
      }
    }
  } else {
    _Float16* op = Vs + (size_t)bz * NN * CC;
#pragma unroll
    for (int mb = 0; mb < 4; mb++) {
      int nq0 = m0 + wm + mb * 16 + quad * 4;  // spatial (k-dim), mult of 4
      const int kt = nq0 >> 5, krel = nq0 & 31;
      const int hk = krel >> 4, hh = (krel >> 3) & 1, j0 = krel & 7;
#pragma unroll
      for (int nb = 0; nb < 4; nb++) {
        int d = n0 + wn + nb * 16 + l15;  // channel
        int ql_ = d & 31, g = (d >> 5) & 7;
        float bv = bias[d];
        half4 pk;
        pk[0] = (_Float16)(acc[mb][nb][0] + bv);
        pk[1] = (_Float16)(acc[mb][nb][1] + bv);
        pk[2] = (_Float16)(acc[mb][nb][2] + bv);
        pk[3] = (_Float16)(acc[mb][nb][3] + bv);
        size_t idx = (((size_t)(kt * 8 + g) * 2 + hk) * 64 + ql_ + 32 * hh) * 8 + j0;
        *(half4*)(op + idx) = pk;
      }
    }
  }
}

// ---------------------------------------------------------------------------
// Flash attention v6: frag-major LDS (zero bank conflicts, zero padding).
// Per 32k-tile: K tile 16KB | V tile 16KB (dbuf) | P 2KB/wave. Linear staging.
// S(t) interleaved with PV(t-1); lazy softmax; normalized fp16 partials + (m,l).
// grid (32 qtiles, 4 chunks, NB), 256 threads, 2 barriers/iter.
// ---------------------------------------------------------------------------
__global__ __launch_bounds__(256, 2) void k_attn(const _Float16* __restrict__ Q,
                                                 const _Float16* __restrict__ K,
                                                 const _Float16* __restrict__ Vt,
                                                 _Float16* __restrict__ Opart,
                                                 float2* __restrict__ Ml) {
  __shared__ _Float16 smem[8192 * 3 + 4096];  // K 16KB | V dbuf 32KB | P 8KB = 56KB
  const int tid = threadIdx.x;
  const int wave = tid >> 6, lane = tid & 63;
  _Float16* Kl = smem;
  _Float16* Plw = smem + 3 * 8192 + wave * 1024;  // [ks 2][lane 64][8]

  const int qt = blockIdx.x, ck = blockIdx.y, b = blockIdx.z;
  const int ql = lane & 31, h = lane >> 5;
  const int q0 = qt * 128 + wave * 32;
  const _Float16* Qb = Q + (size_t)b * NN * CC;
  const _Float16* Kb = K + (size_t)b * NN * CC;
  const _Float16* Vb = Vt + (size_t)b * NN * CC;
  const int kt_base = ck * (1024 / 32);

  // Q B-frags from swizzled layout: tile ktq = q0>>5, contiguous 1KB per cs
  const int ktq = q0 >> 5;
  half8 qf[16];
#pragma unroll
  for (int cs = 0; cs < 16; cs++)
    qf[cs] = *(const half8*)(Qb + ((size_t)(ktq * 16 + cs) * 64 + lane) * 8);

  float16v Oa[8];
#pragma unroll
  for (int g = 0; g < 8; g++)
#pragma unroll
    for (int i = 0; i < 16; i++) Oa[g][i] = 0.f;

  float m_run = -1e30f, l_run = 0.f;

  intx4 kpre[4], vpre[4];
  {
    const _Float16* Kt = Kb + (size_t)kt_base * 8192;
    const _Float16* Vtile = Vb + (size_t)kt_base * 8192;
#pragma unroll
    for (int p = 0; p < 4; p++) {
      kpre[p] = *(const intx4*)(Kt + tid * 8 + p * 2048);
      vpre[p] = *(const intx4*)(Vtile + tid * 8 + p * 2048);
    }
  }

  for (int t = 0; t < KITERS; t++) {
    const int vb = t & 1;
    _Float16* Vw = smem + (1 + vb) * 8192;
    __syncthreads();  // A: all waves done with Kl(t-1), Vl[vb](t-2)
#pragma unroll
    for (int p = 0; p < 4; p++) {
      *(intx4*)(Kl + tid * 8 + p * 2048) = kpre[p];
      *(intx4*)(Vw + tid * 8 + p * 2048) = vpre[p];
    }
    __syncthreads();  // B: tile t visible
    if (t + 1 < KITERS) {
      const _Float16* Kt = Kb + (size_t)(kt_base + t + 1) * 8192;
      const _Float16* Vtile = Vb + (size_t)(kt_base + t + 1) * 8192;
#pragma unroll
      for (int p = 0; p < 4; p++) {
        kpre[p] = *(const intx4*)(Kt + tid * 8 + p * 2048);
        vpre[p] = *(const intx4*)(Vtile + tid * 8 + p * 2048);
      }
    }

    // ---- MFMA burst: S(t) interleaved with PV(t-1)
    float16v s;
#pragma unroll
    for (int i = 0; i < 16; i++) s[i] = 0.f;
    if (t > 0) {
      _Float16* Vr = smem + (1 + (vb ^ 1)) * 8192;  // V buffer of tile t-1
      half8 pf0 = *(const half8*)(Plw + lane * 8);
      half8 pf1 = *(const half8*)(Plw + 512 + lane * 8);
#pragma unroll
      for (int u = 0; u < 8; u++) {
        half8 kfa = *(const half8*)(Kl + (2 * u) * 512 + lane * 8);
        s = __builtin_amdgcn_mfma_f32_32x32x16_f16(kfa, qf[2 * u], s, 0, 0, 0);
        half8 vfa = *(const half8*)(Vr + (u * 2) * 512 + lane * 8);
        Oa[u] = __builtin_amdgcn_mfma_f32_32x32x16_f16(vfa, pf0, Oa[u], 0, 0, 0);
        half8 kfb = *(const half8*)(Kl + (2 * u + 1) * 512 + lane * 8);
        s = __builtin_amdgcn_mfma_f32_32x32x16_f16(kfb, qf[2 * u + 1], s, 0, 0, 0);
        half8 vfb = *(const half8*)(Vr + (u * 2 + 1) * 512 + lane * 8);
        Oa[u] = __builtin_amdgcn_mfma_f32_32x32x16_f16(vfb, pf1, Oa[u], 0, 0, 0);
      }
    } else {
#pragma unroll
      for (int cs = 0; cs < 16; cs++) {
        half8 kf = *(const half8*)(Kl + cs * 512 + lane * 8);
        s = __builtin_amdgcn_mfma_f32_32x32x16_f16(kf, qf[cs], s, 0, 0, 0);
      }
    }

    // ---- lazy online softmax (per-lane), tree reductions
    float t0 = fmaxf(s[0], s[1]), t1 = fmaxf(s[2], s[3]);
    float t2 = fmaxf(s[4], s[5]), t3 = fmaxf(s[6], s[7]);
    float t4 = fmaxf(s[8], s[9]), t5 = fmaxf(s[10], s[11]);
    float t6 = fmaxf(s[12], s[13]), t7 = fmaxf(s[14], s[15]);
    t0 = fmaxf(t0, t1); t2 = fmaxf(t2, t3); t4 = fmaxf(t4, t5); t6 = fmaxf(t6, t7);
    float tmax = fmaxf(fmaxf(t0, t2), fmaxf(t4, t6));
    tmax = fmaxf(tmax, __shfl_xor(tmax, 32));
    bool need = tmax > m_run + 8.0f;
    if (__any((int)need)) {
      float mN = need ? tmax : m_run;
      float alpha = __expf(m_run - mN);
      m_run = mN;
      l_run *= alpha;
#pragma unroll
      for (int g = 0; g < 8; g++)
#pragma unroll
        for (int i = 0; i < 16; i++) Oa[g][i] *= alpha;
    }
#pragma unroll
    for (int i = 0; i < 16; i++) s[i] = __expf(s[i] - m_run);
    float u0 = (s[0] + s[1]) + (s[2] + s[3]);
    float u1 = (s[4] + s[5]) + (s[6] + s[7]);
    float u2 = (s[8] + s[9]) + (s[10] + s[11]);
    float u3 = (s[12] + s[13]) + (s[14] + s[15]);
    float ts = (u0 + u1) + (u2 + u3);
    ts += __shfl_xor(ts, 32);
    l_run += ts;
    // P(t) -> Plw frag-major: k = (r&3)+8*(r>>2)+4h; [ks=k>>4][ql+32*((k>>3)&1)][k&7]
#pragma unroll
    for (int r = 0; r < 16; r += 2) {
      half2v pk;
      pk[0] = (_Float16)s[r];
      pk[1] = (_Float16)s[r + 1];
      int k = (r & 3) + 8 * (r >> 2) + 4 * h;
      *(half2v*)(Plw + (k >> 4) * 512 + (ql + 32 * ((k >> 3) & 1)) * 8 + (k & 7)) = pk;
    }
  }

  // ---- tail: PV for last tile
  {
    _Float16* Vr = smem + (1 + ((KITERS - 1) & 1)) * 8192;
    half8 pf0 = *(const half8*)(Plw + lane * 8);
    half8 pf1 = *(const half8*)(Plw + 512 + lane * 8);
#pragma unroll
    for (int u = 0; u < 8; u++) {
      half8 vfa = *(const half8*)(Vr + (u * 2) * 512 + lane * 8);
      Oa[u] = __builtin_amdgcn_mfma_f32_32x32x16_f16(vfa, pf0, Oa[u], 0, 0, 0);
      half8 vfb = *(const half8*)(Vr + (u * 2 + 1) * 512 + lane * 8);
      Oa[u] = __builtin_amdgcn_mfma_f32_32x32x16_f16(vfb, pf1, Oa[u], 0, 0, 0);
    }
  }

  // ---- epilogue: normalize, per-wave LDS transpose, coalesced store
  float invl = 1.f / l_run;
  __syncthreads();
  float* ot = (float*)smem + wave * (32 * 33);
  _Float16* Opb = Opart + ((size_t)ck * NB + b) * NN * CC;
  const int qr = lane >> 1;
  const int chalf = (lane & 1) * 16;
#pragma unroll
  for (int g = 0; g < 8; g++) {
#pragma unroll
    for (int r = 0; r < 16; r++)
      ot[((r & 3) + 8 * (r >> 2) + 4 * h) * 33 + ql] = Oa[g][r] * invl;
    __builtin_amdgcn_s_waitcnt(WAIT_LGKM0);  // cross-lane RAW (wave-sync LDS)
    half8 o0, o1;
#pragma unroll
    for (int i = 0; i < 8; i++) o0[i] = (_Float16)ot[(chalf + i) * 33 + qr];
#pragma unroll
    for (int i = 0; i < 8; i++) o1[i] = (_Float16)ot[(chalf + 8 + i) * 33 + qr];
    _Float16* gp = Opb + (size_t)(q0 + qr) * CC + g * 32 + chalf;
    *(half8*)gp = o0;
    *(half8*)(gp + 8) = o1;
    __builtin_amdgcn_s_waitcnt(WAIT_LGKM0);  // WAR before next-g overwrite
  }
  if (h == 0) {
    float2 ml; ml.x = m_run; ml.y = l_run;
    Ml[((size_t)ck * NB + b) * NN + q0 + ql] = ml;
  }
}

// ---------------------------------------------------------------------------
// Final conv with fused split-K merge: A-rows merged on the fly.
// out[b][d][n] fp32 = Wo . O^T + bo. grid (64, NB), 256 threads.
// ---------------------------------------------------------------------------
__global__ __launch_bounds__(256, 2) void k_out(const _Float16* __restrict__ Opart,
                                                const float2* __restrict__ Ml,
                                                const float* __restrict__ Wo,
                                                const float* __restrict__ bo,
                                                float* __restrict__ out) {
  __shared__ _Float16 As[128][40];
  __shared__ _Float16 Bs[128][40];
  const int bz = blockIdx.y;
  const int mt = blockIdx.x >> 1, nt = blockIdx.x & 1;
  const int m0 = mt * 128, n0 = nt * 128;
  const int tid = threadIdx.x;
  const int wave = tid >> 6, lane = tid & 63, quad = lane >> 4, l15 = lane & 15;
  const int wm = (wave >> 1) * 64, wn = (wave & 1) * 64;

  floatx4 acc[4][4];
#pragma unroll
  for (int i = 0; i < 4; i++)
#pragma unroll
    for (int j = 0; j < 4; j++) acc[i][j] = (floatx4){0.f, 0.f, 0.f, 0.f};

  const int srow = tid >> 1;
  const int shalf = (tid & 1) * 16;

  // merge weights for this thread's fixed row q = m0 + srow
  const size_t qi = (size_t)bz * NN + m0 + srow;
  float2 a0 = Ml[qi], a1 = Ml[(size_t)NB * NN + qi];
  float2 a2 = Ml[(size_t)2 * NB * NN + qi], a3 = Ml[(size_t)3 * NB * NN + qi];
  float M = fmaxf(fmaxf(a0.x, a1.x), fmaxf(a2.x, a3.x));
  float w0 = __expf(a0.x - M) * a0.y, w1 = __expf(a1.x - M) * a1.y;
  float w2 = __expf(a2.x - M) * a2.y, w3 = __expf(a3.x - M) * a3.y;
  float inv = 1.f / (w0 + w1 + w2 + w3);
  w0 *= inv; w1 *= inv; w2 *= inv; w3 *= inv;
  const size_t ps = (size_t)NB * NN * CC;
  const _Float16* prow = Opart + qi * CC;

  for (int kk = 0; kk < 256; kk += 32) {
    const _Float16* pr = prow + kk + shalf;
    half8 p0a = *(const half8*)pr,            p0b = *(const half8*)(pr + 8);
    half8 p1a = *(const half8*)(pr + ps),     p1b = *(const half8*)(pr + ps + 8);
    half8 p2a = *(const half8*)(pr + 2 * ps), p2b = *(const half8*)(pr + 2 * ps + 8);
    half8 p3a = *(const half8*)(pr + 3 * ps), p3b = *(const half8*)(pr + 3 * ps + 8);
    half8 ma, mb2;
#pragma unroll
    for (int i = 0; i < 8; i++) {
      ma[i] = (_Float16)(w0 * (float)p0a[i] + w1 * (float)p1a[i] +
                         w2 * (float)p2a[i] + w3 * (float)p3a[i]);
      mb2[i] = (_Float16)(w0 * (float)p0b[i] + w1 * (float)p1b[i] +
                          w2 * (float)p2b[i] + w3 * (float)p3b[i]);
    }
    half8 b_lo, b_hi;
    cvt16((const float4*)(Wo + (size_t)(n0 + srow) * 256 + kk + shalf), b_lo, b_hi);
    __syncthreads();
    *(half8*)&As[srow][shalf] = ma;
    *(half8*)&As[srow][shalf + 8] = mb2;
    *(half8*)&Bs[srow][shalf] = b_lo;
    *(half8*)&Bs[srow][shalf + 8] = b_hi;
    __syncthreads();
    half8 af[4], bfr[4];
#pragma unroll
    for (int mb = 0; mb < 4; mb++) af[mb] = *(const half8*)&As[wm + mb * 16 + l15][quad * 8];
#pragma unroll
    for (int nb = 0; nb < 4; nb++) bfr[nb] = *(const half8*)&Bs[wn + nb * 16 + l15][quad * 8];
#pragma unroll
    for (int mb = 0; mb < 4; mb++)
#pragma unroll
      for (int nb = 0; nb < 4; nb++)
        acc[mb][nb] = __builtin_amdgcn_mfma_f32_16x16x32_f16(af[mb], bfr[nb], acc[mb][nb], 0, 0, 0);
  }

  float* op = out + (size_t)bz * NN * CC;
#pragma unroll
  for (int mb = 0; mb < 4; mb++) {
    int nq0 = m0 + wm + mb * 16 + quad * 4;  // spatial
#pragma unroll
    for (int nb = 0; nb < 4; nb++) {
      int d = n0 + wn + nb * 16 + l15;
      float bv = bo[d];
      floatx4 pk;
      pk[0] = acc[mb][nb][0] + bv;
      pk[1] = acc[mb][nb][1] + bv;
      pk[2] = acc[mb][nb][2] + bv;
      pk[3] = acc[mb][nb][3] + bv;
      *(floatx4*)(op + (size_t)d * NN + nq0) = pk;
    }
  }
}

// ---------------------------------------------------------------------------
extern "C" void kernel_launch(void* const* d_in, const int* in_sizes, int n_in,
                              void* d_out, int out_size, void* d_ws, size_t ws_size,
                              hipStream_t stream) {
  const float* Fc = (const float*)d_in[0];
  const float* Fs = (const float*)d_in[1];
  const float* Wf = (const float*)d_in[2];
  const float* bf_ = (const float*)d_in[3];
  const float* Wg = (const float*)d_in[4];
  const float* bg = (const float*)d_in[5];
  const float* Wh = (const float*)d_in[6];
  const float* bh = (const float*)d_in[7];
  const float* Wo = (const float*)d_in[8];
  const float* bo = (const float*)d_in[9];

  char* ws = (char*)d_ws;
  const size_t sz = (size_t)NB * NN * CC * sizeof(_Float16);  // 8 MB per plane
  _Float16* Xct = (_Float16*)(ws + 0 * sz);   // -> attn partial ck0
  _Float16* Xst = (_Float16*)(ws + 1 * sz);   // -> attn partial ck1
  _Float16* Opart = Xct;                      // partials ck0..3 = planes 0..3
  _Float16* Qs = (_Float16*)(ws + 4 * sz);    // swizzled
  _Float16* Ks = (_Float16*)(ws + 5 * sz);
  _Float16* Vs = (_Float16*)(ws + 6 * sz);
  float2* Ml = (float2*)(ws + 7 * sz);        // 512 KB

  k_transpose<<<dim3(64, 4, 8), 256, 0, stream>>>(Fc, Fs, Xct, Xst);
  k_qkv<<<dim3(64, NB, 3), 256, 0, stream>>>(Wf, Wg, Wh, Xct, Xst, bf_, bg, bh, Qs, Ks, Vs);
  k_attn<<<dim3(32, 4, NB), 256, 0, stream>>>(Qs, Ks, Vs, Opart, Ml);
  k_out<<<dim3(64, NB), 256, 0, stream>>>(Opart, Ml, Wo, bo, (float*)d_out);
}

// Round 8
// 212.060 us; speedup vs baseline: 3.0597x; 1.0211x over previous
//
#include <hip/hip_runtime.h>
#include <stdint.h>

#define NB 4
#define CC 256
#define NN 4096   // H*W = 64*64
#define KITERS 32 // k-steps per attention chunk (chunk = 1024)
#define WAIT_LGKM0 0xC07F  // s_waitcnt lgkmcnt(0), vmcnt/expcnt untouched

typedef __attribute__((ext_vector_type(8))) _Float16 half8;   // MFMA A/B frag (4 VGPR)
typedef __attribute__((ext_vector_type(4))) _Float16 half4;   // 8B packed store
typedef __attribute__((ext_vector_type(2))) _Float16 half2v;
typedef __attribute__((ext_vector_type(4))) float floatx4;    // 16x16 acc
typedef __attribute__((ext_vector_type(16))) float float16v;  // 32x32 acc
typedef __attribute__((ext_vector_type(4))) int intx4;        // 16B copy

__device__ __forceinline__ void cvt16v(float4 a, float4 b, float4 c, float4 d,
                                       half8& lo, half8& hi) {
  lo[0] = (_Float16)a.x; lo[1] = (_Float16)a.y; lo[2] = (_Float16)a.z; lo[3] = (_Float16)a.w;
  lo[4] = (_Float16)b.x; lo[5] = (_Float16)b.y; lo[6] = (_Float16)b.z; lo[7] = (_Float16)b.w;
  hi[0] = (_Float16)c.x; hi[1] = (_Float16)c.y; hi[2] = (_Float16)c.z; hi[3] = (_Float16)c.w;
  hi[4] = (_Float16)d.x; hi[5] = (_Float16)d.y; hi[6] = (_Float16)d.z; hi[7] = (_Float16)d.w;
}

// ---------------------------------------------------------------------------
// Fused transpose + Q/K/V projections -> FRAG-MAJOR (swizzled) outputs.
// Reads F [b][c][n] fp32 DIRECTLY; per k-iter, transposes a 32c x 128n tile
// through LDS (fp32 tmp, padded) into fp16 frag rows. No Xt intermediate.
// z=0: Q = Wf.Fc   z=1: K = Wg.Fs   z=2: Vt = (Fs^T.Wh^T)^T
// Q/K swizzle: idx = ((kt*16 + cs)*64 + ql + 32*hh)*8 + j
// V swizzle:   idx = (((kt*8 + g)*2 + hk)*64 + ql + 32*hh)*8 + j
// grid (64, NB, 3), 256 threads, 3 blocks/CU.
// ---------------------------------------------------------------------------
__global__ __launch_bounds__(256, 3) void k_qkv(const float* __restrict__ Fc,
                                                const float* __restrict__ Fs,
                                                const float* __restrict__ Wf,
                                                const float* __restrict__ Wg,
                                                const float* __restrict__ Wh,
                                                const float* __restrict__ bf,
                                                const float* __restrict__ bg,
                                                const float* __restrict__ bh,
                                                _Float16* __restrict__ Qs,
                                                _Float16* __restrict__ Ks,
                                                _Float16* __restrict__ Vs) {
  __shared__ float tmp[32][132];     // 16.9 KB fp32 transpose staging
  __shared__ _Float16 As[128][40];   // 10 KB
  __shared__ _Float16 Bs[128][40];   // 10 KB
  const int z = blockIdx.z, bz = blockIdx.y;
  const float* F = ((z == 0) ? Fc : Fs) + (size_t)bz * CC * NN;
  const float* W = (z == 0) ? Wf : ((z == 1) ? Wg : Wh);
  const float* bias = (z == 0) ? bf : ((z == 1) ? bg : bh);
  int mt, nt;
  if (z < 2) { mt = blockIdx.x >> 5; nt = blockIdx.x & 31; }  // M=d(256), N=n(4096)
  else       { mt = blockIdx.x >> 1; nt = blockIdx.x & 1;  }  // M=n(4096), N=d(256)
  const int m0 = mt * 128, n0 = nt * 128;
  const int xn0 = (z < 2) ? n0 : m0;  // spatial base of the F tile (X side)
  const int wd0 = (z < 2) ? m0 : n0;  // W row base (channel side)
  const int tid = threadIdx.x;
  const int wave = tid >> 6, lane = tid & 63, quad = lane >> 4, l15 = lane & 15;
  const int wm = (wave >> 1) * 64, wn = (wave & 1) * 64;

  floatx4 acc[4][4];
#pragma unroll
  for (int i = 0; i < 4; i++)
#pragma unroll
    for (int j = 0; j < 4; j++) acc[i][j] = (floatx4){0.f, 0.f, 0.f, 0.f};

  // staging indices
  const int srow = tid >> 1, shalf = (tid & 1) * 16;   // W staging
  const int fc = tid >> 3, fn = (tid & 7) * 16;        // F load (c-row, n-off)
  const int xr = tid >> 1, xh = (tid & 1) * 16;        // transposed read

  // preload kk=0
  float4 wr0, wr1, wr2, wr3, fr0, fr1, fr2, fr3;
  {
    const float4* wp = (const float4*)(W + (size_t)(wd0 + srow) * 256 + 0 + shalf);
    wr0 = wp[0]; wr1 = wp[1]; wr2 = wp[2]; wr3 = wp[3];
    const float4* fp = (const float4*)(F + (size_t)(0 + fc) * NN + xn0 + fn);
    fr0 = fp[0]; fr1 = fp[1]; fr2 = fp[2]; fr3 = fp[3];
  }

  for (int kk = 0; kk < 256; kk += 32) {
    __syncthreads();  // 1: prev frag+tmp reads done
    *(float4*)&tmp[fc][fn + 0] = fr0;
    *(float4*)&tmp[fc][fn + 4] = fr1;
    *(float4*)&tmp[fc][fn + 8] = fr2;
    *(float4*)&tmp[fc][fn + 12] = fr3;
    half8 w_lo, w_hi;
    cvt16v(wr0, wr1, wr2, wr3, w_lo, w_hi);
    if (z < 2) {
      *(half8*)&As[srow][shalf] = w_lo;
      *(half8*)&As[srow][shalf + 8] = w_hi;
    } else {
      *(half8*)&Bs[srow][shalf] = w_lo;
      *(half8*)&Bs[srow][shalf + 8] = w_hi;
    }
    __syncthreads();  // 2: tmp + W-side visible
    if (kk + 32 < 256) {  // prefetch next iter
      const float4* wp = (const float4*)(W + (size_t)(wd0 + srow) * 256 + kk + 32 + shalf);
      wr0 = wp[0]; wr1 = wp[1]; wr2 = wp[2]; wr3 = wp[3];
      const float4* fp = (const float4*)(F + (size_t)(kk + 32 + fc) * NN + xn0 + fn);
      fr0 = fp[0]; fr1 = fp[1]; fr2 = fp[2]; fr3 = fp[3];
    }
    // transposed read + cvt -> X-side frag rows
    half8 xlo, xhi;
#pragma unroll
    for (int i = 0; i < 8; i++) xlo[i] = (_Float16)tmp[xh + i][xr];
#pragma unroll
    for (int i = 0; i < 8; i++) xhi[i] = (_Float16)tmp[xh + 8 + i][xr];
    if (z < 2) {
      *(half8*)&Bs[xr][xh] = xlo;
      *(half8*)&Bs[xr][xh + 8] = xhi;
    } else {
      *(half8*)&As[xr][xh] = xlo;
      *(half8*)&As[xr][xh + 8] = xhi;
    }
    __syncthreads();  // 3: As/Bs complete
    half8 af[4], bfr[4];
#pragma unroll
    for (int mb = 0; mb < 4; mb++) af[mb] = *(const half8*)&As[wm + mb * 16 + l15][quad * 8];
#pragma unroll
    for (int nb = 0; nb < 4; nb++) bfr[nb] = *(const half8*)&Bs[wn + nb * 16 + l15][quad * 8];
#pragma unroll
    for (int mb = 0; mb < 4; mb++)
#pragma unroll
      for (int nb = 0; nb < 4; nb++)
        acc[mb][nb] = __builtin_amdgcn_mfma_f32_16x16x32_f16(af[mb], bfr[nb], acc[mb][nb], 0, 0, 0);
  }

  if (z < 2) {
    _Float16* op = (z == 0 ? Qs : Ks) + (size_t)bz * NN * CC;
#pragma unroll
    for (int mb = 0; mb < 4; mb++) {
      int d0 = m0 + wm + mb * 16 + quad * 4;  // channel, mult of 4
      float b0 = bias[d0], b1 = bias[d0 + 1], b2 = bias[d0 + 2], b3 = bias[d0 + 3];
      const int cs = d0 >> 4, hh = (d0 >> 3) & 1, j0 = d0 & 7;
#pragma unroll
      for (int nb = 0; nb < 4; nb++) {
        int n_ = n0 + wn + nb * 16 + l15;  // spatial
        int kt = n_ >> 5, ql_ = n_ & 31;
        half4 pk;
        pk[0] = (_Float16)(acc[mb][nb][0] + b0);
        pk[1] = (_Float16)(acc[mb][nb][1] + b1);
        pk[2] = (_Float16)(acc[mb][nb][2] + b2);
        pk[3] = (_Float16)(acc[mb][nb][3] + b3);
        size_t idx = ((size_t)(kt * 16 + cs) * 64 + ql_ + 32 * hh) * 8 + j0;
        *(half4*)(op + idx) = pk;
      }
    }
  } else {
    _Float16* op = Vs + (size_t)bz * NN * CC;
#pragma unroll
    for (int mb = 0; mb < 4; mb++) {
      int nq0 = m0 + wm + mb * 16 + quad * 4;  // spatial (k-dim), mult of 4
      const int kt = nq0 >> 5, krel = nq0 & 31;
      const int hk = krel >> 4, hh = (krel >> 3) & 1, j0 = krel & 7;
#pragma unroll
      for (int nb = 0; nb < 4; nb++) {
        int d = n0 + wn + nb * 16 + l15;  // channel
        int ql_ = d & 31, g = (d >> 5) & 7;
        float bv = bias[d];
        half4 pk;
        pk[0] = (_Float16)(acc[mb][nb][0] + bv);
        pk[1] = (_Float16)(acc[mb][nb][1] + bv);
        pk[2] = (_Float16)(acc[mb][nb][2] + bv);
        pk[3] = (_Float16)(acc[mb][nb][3] + bv);
        size_t idx = (((size_t)(kt * 8 + g) * 2 + hk) * 64 + ql_ + 32 * hh) * 8 + j0;
        *(half4*)(op + idx) = pk;
      }
    }
  }
}

// ---------------------------------------------------------------------------
// Flash attention v7: frag-major LDS, S split into two 8-deep MFMA chains.
// grid (32 qtiles, 4 chunks, NB), 256 threads, 2 barriers/iter.
// ---------------------------------------------------------------------------
__global__ __launch_bounds__(256, 2) void k_attn(const _Float16* __restrict__ Q,
                                                 const _Float16* __restrict__ K,
                                                 const _Float16* __restrict__ Vt,
                                                 _Float16* __restrict__ Opart,
                                                 float2* __restrict__ Ml) {
  __shared__ _Float16 smem[8192 * 3 + 4096];  // K 16KB | V dbuf 32KB | P 8KB
  const int tid = threadIdx.x;
  const int wave = tid >> 6, lane = tid & 63;
  _Float16* Kl = smem;
  _Float16* Plw = smem + 3 * 8192 + wave * 1024;  // [ks 2][lane 64][8]

  const int qt = blockIdx.x, ck = blockIdx.y, b = blockIdx.z;
  const int ql = lane & 31, h = lane >> 5;
  const int q0 = qt * 128 + wave * 32;
  const _Float16* Qb = Q + (size_t)b * NN * CC;
  const _Float16* Kb = K + (size_t)b * NN * CC;
  const _Float16* Vb = Vt + (size_t)b * NN * CC;
  const int kt_base = ck * (1024 / 32);

  const int ktq = q0 >> 5;
  half8 qf[16];
#pragma unroll
  for (int cs = 0; cs < 16; cs++)
    qf[cs] = *(const half8*)(Qb + ((size_t)(ktq * 16 + cs) * 64 + lane) * 8);

  float16v Oa[8];
#pragma unroll
  for (int g = 0; g < 8; g++)
#pragma unroll
    for (int i = 0; i < 16; i++) Oa[g][i] = 0.f;

  float m_run = -1e30f, l_run = 0.f;

  intx4 kpre[4], vpre[4];
  {
    const _Float16* Kt = Kb + (size_t)kt_base * 8192;
    const _Float16* Vtile = Vb + (size_t)kt_base * 8192;
#pragma unroll
    for (int p = 0; p < 4; p++) {
      kpre[p] = *(const intx4*)(Kt + tid * 8 + p * 2048);
      vpre[p] = *(const intx4*)(Vtile + tid * 8 + p * 2048);
    }
  }

  for (int t = 0; t < KITERS; t++) {
    const int vb = t & 1;
    _Float16* Vw = smem + (1 + vb) * 8192;
    __syncthreads();  // A
#pragma unroll
    for (int p = 0; p < 4; p++) {
      *(intx4*)(Kl + tid * 8 + p * 2048) = kpre[p];
      *(intx4*)(Vw + tid * 8 + p * 2048) = vpre[p];
    }
    __syncthreads();  // B
    if (t + 1 < KITERS) {
      const _Float16* Kt = Kb + (size_t)(kt_base + t + 1) * 8192;
      const _Float16* Vtile = Vb + (size_t)(kt_base + t + 1) * 8192;
#pragma unroll
      for (int p = 0; p < 4; p++) {
        kpre[p] = *(const intx4*)(Kt + tid * 8 + p * 2048);
        vpre[p] = *(const intx4*)(Vtile + tid * 8 + p * 2048);
      }
    }

    // ---- MFMA burst: S(t) (two 8-deep chains) interleaved with PV(t-1)
    float16v s, s2;
#pragma unroll
    for (int i = 0; i < 16; i++) { s[i] = 0.f; s2[i] = 0.f; }
    if (t > 0) {
      _Float16* Vr = smem + (1 + (vb ^ 1)) * 8192;
      half8 pf0 = *(const half8*)(Plw + lane * 8);
      half8 pf1 = *(const half8*)(Plw + 512 + lane * 8);
#pragma unroll
      for (int u = 0; u < 8; u++) {
        half8 kfa = *(const half8*)(Kl + (2 * u) * 512 + lane * 8);
        s = __builtin_amdgcn_mfma_f32_32x32x16_f16(kfa, qf[2 * u], s, 0, 0, 0);
        half8 vfa = *(const half8*)(Vr + (u * 2) * 512 + lane * 8);
        Oa[u] = __builtin_amdgcn_mfma_f32_32x32x16_f16(vfa, pf0, Oa[u], 0, 0, 0);
        half8 kfb = *(const half8*)(Kl + (2 * u + 1) * 512 + lane * 8);
        s2 = __builtin_amdgcn_mfma_f32_32x32x16_f16(kfb, qf[2 * u + 1], s2, 0, 0, 0);
        half8 vfb = *(const half8*)(Vr + (u * 2 + 1) * 512 + lane * 8);
        Oa[u] = __builtin_amdgcn_mfma_f32_32x32x16_f16(vfb, pf1, Oa[u], 0, 0, 0);
      }
    } else {
#pragma unroll
      for (int cs = 0; cs < 16; cs += 2) {
        half8 kfa = *(const half8*)(Kl + cs * 512 + lane * 8);
        s = __builtin_amdgcn_mfma_f32_32x32x16_f16(kfa, qf[cs], s, 0, 0, 0);
        half8 kfb = *(const half8*)(Kl + (cs + 1) * 512 + lane * 8);
        s2 = __builtin_amdgcn_mfma_f32_32x32x16_f16(kfb, qf[cs + 1], s2, 0, 0, 0);
      }
    }
#pragma unroll
    for (int i = 0; i < 16; i++) s[i] += s2[i];

    // ---- lazy online softmax (per-lane), tree reductions
    float t0 = fmaxf(s[0], s[1]), t1 = fmaxf(s[2], s[3]);
    float t2 = fmaxf(s[4], s[5]), t3 = fmaxf(s[6], s[7]);
    float t4 = fmaxf(s[8], s[9]), t5 = fmaxf(s[10], s[11]);
    float t6 = fmaxf(s[12], s[13]), t7 = fmaxf(s[14], s[15]);
    t0 = fmaxf(t0, t1); t2 = fmaxf(t2, t3); t4 = fmaxf(t4, t5); t6 = fmaxf(t6, t7);
    float tmax = fmaxf(fmaxf(t0, t2), fmaxf(t4, t6));
    tmax = fmaxf(tmax, __shfl_xor(tmax, 32));
    bool need = tmax > m_run + 8.0f;
    if (__any((int)need)) {
      float mN = need ? tmax : m_run;
      float alpha = __expf(m_run - mN);
      m_run = mN;
      l_run *= alpha;
#pragma unroll
      for (int g = 0; g < 8; g++)
#pragma unroll
        for (int i = 0; i < 16; i++) Oa[g][i] *= alpha;
    }
#pragma unroll
    for (int i = 0; i < 16; i++) s[i] = __expf(s[i] - m_run);
    float u0 = (s[0] + s[1]) + (s[2] + s[3]);
    float u1 = (s[4] + s[5]) + (s[6] + s[7]);
    float u2 = (s[8] + s[9]) + (s[10] + s[11]);
    float u3 = (s[12] + s[13]) + (s[14] + s[15]);
    float ts = (u0 + u1) + (u2 + u3);
    ts += __shfl_xor(ts, 32);
    l_run += ts;
#pragma unroll
    for (int r = 0; r < 16; r += 2) {
      half2v pk;
      pk[0] = (_Float16)s[r];
      pk[1] = (_Float16)s[r + 1];
      int k = (r & 3) + 8 * (r >> 2) + 4 * h;
      *(half2v*)(Plw + (k >> 4) * 512 + (ql + 32 * ((k >> 3) & 1)) * 8 + (k & 7)) = pk;
    }
  }

  // ---- tail: PV for last tile
  {
    _Float16* Vr = smem + (1 + ((KITERS - 1) & 1)) * 8192;
    half8 pf0 = *(const half8*)(Plw + lane * 8);
    half8 pf1 = *(const half8*)(Plw + 512 + lane * 8);
#pragma unroll
    for (int u = 0; u < 8; u++) {
      half8 vfa = *(const half8*)(Vr + (u * 2) * 512 + lane * 8);
      Oa[u] = __builtin_amdgcn_mfma_f32_32x32x16_f16(vfa, pf0, Oa[u], 0, 0, 0);
      half8 vfb = *(const half8*)(Vr + (u * 2 + 1) * 512 + lane * 8);
      Oa[u] = __builtin_amdgcn_mfma_f32_32x32x16_f16(vfb, pf1, Oa[u], 0, 0, 0);
    }
  }

  // ---- epilogue: normalize, per-wave LDS transpose, coalesced store
  float invl = 1.f / l_run;
  __syncthreads();
  float* ot = (float*)smem + wave * (32 * 33);
  _Float16* Opb = Opart + ((size_t)ck * NB + b) * NN * CC;
  const int qr = lane >> 1;
  const int chalf = (lane & 1) * 16;
#pragma unroll
  for (int g = 0; g < 8; g++) {
#pragma unroll
    for (int r = 0; r < 16; r++)
      ot[((r & 3) + 8 * (r >> 2) + 4 * h) * 33 + ql] = Oa[g][r] * invl;
    __builtin_amdgcn_s_waitcnt(WAIT_LGKM0);
    half8 o0, o1;
#pragma unroll
    for (int i = 0; i < 8; i++) o0[i] = (_Float16)ot[(chalf + i) * 33 + qr];
#pragma unroll
    for (int i = 0; i < 8; i++) o1[i] = (_Float16)ot[(chalf + 8 + i) * 33 + qr];
    _Float16* gp = Opb + (size_t)(q0 + qr) * CC + g * 32 + chalf;
    *(half8*)gp = o0;
    *(half8*)(gp + 8) = o1;
    __builtin_amdgcn_s_waitcnt(WAIT_LGKM0);
  }
  if (h == 0) {
    float2 ml; ml.x = m_run; ml.y = l_run;
    Ml[((size_t)ck * NB + b) * NN + q0 + ql] = ml;
  }
}

// ---------------------------------------------------------------------------
// Final conv with fused split-K merge. out[b][d][n] fp32 = Wo . O^T + bo.
// grid (64, NB), 256 threads.
// ---------------------------------------------------------------------------
__global__ __launch_bounds__(256, 2) void k_out(const _Float16* __restrict__ Opart,
                                                const float2* __restrict__ Ml,
                                                const float* __restrict__ Wo,
                                                const float* __restrict__ bo,
                                                float* __restrict__ out) {
  __shared__ _Float16 As[128][40];
  __shared__ _Float16 Bs[128][40];
  const int bz = blockIdx.y;
  const int mt = blockIdx.x >> 1, nt = blockIdx.x & 1;
  const int m0 = mt * 128, n0 = nt * 128;
  const int tid = threadIdx.x;
  const int wave = tid >> 6, lane = tid & 63, quad = lane >> 4, l15 = lane & 15;
  const int wm = (wave >> 1) * 64, wn = (wave & 1) * 64;

  floatx4 acc[4][4];
#pragma unroll
  for (int i = 0; i < 4; i++)
#pragma unroll
    for (int j = 0; j < 4; j++) acc[i][j] = (floatx4){0.f, 0.f, 0.f, 0.f};

  const int srow = tid >> 1;
  const int shalf = (tid & 1) * 16;

  const size_t qi = (size_t)bz * NN + m0 + srow;
  float2 a0 = Ml[qi], a1 = Ml[(size_t)NB * NN + qi];
  float2 a2 = Ml[(size_t)2 * NB * NN + qi], a3 = Ml[(size_t)3 * NB * NN + qi];
  float M = fmaxf(fmaxf(a0.x, a1.x), fmaxf(a2.x, a3.x));
  float w0 = __expf(a0.x - M) * a0.y, w1 = __expf(a1.x - M) * a1.y;
  float w2 = __expf(a2.x - M) * a2.y, w3 = __expf(a3.x - M) * a3.y;
  float inv = 1.f / (w0 + w1 + w2 + w3);
  w0 *= inv; w1 *= inv; w2 *= inv; w3 *= inv;
  const size_t ps = (size_t)NB * NN * CC;
  const _Float16* prow = Opart + qi * CC;

  for (int kk = 0; kk < 256; kk += 32) {
    const _Float16* pr = prow + kk + shalf;
    half8 p0a = *(const half8*)pr,            p0b = *(const half8*)(pr + 8);
    half8 p1a = *(const half8*)(pr + ps),     p1b = *(const half8*)(pr + ps + 8);
    half8 p2a = *(const half8*)(pr + 2 * ps), p2b = *(const half8*)(pr + 2 * ps + 8);
    half8 p3a = *(const half8*)(pr + 3 * ps), p3b = *(const half8*)(pr + 3 * ps + 8);
    half8 ma, mb2;
#pragma unroll
    for (int i = 0; i < 8; i++) {
      ma[i] = (_Float16)(w0 * (float)p0a[i] + w1 * (float)p1a[i] +
                         w2 * (float)p2a[i] + w3 * (float)p3a[i]);
      mb2[i] = (_Float16)(w0 * (float)p0b[i] + w1 * (float)p1b[i] +
                          w2 * (float)p2b[i] + w3 * (float)p3b[i]);
    }
    const float4* wp = (const float4*)(Wo + (size_t)(n0 + srow) * 256 + kk + shalf);
    half8 b_lo, b_hi;
    cvt16v(wp[0], wp[1], wp[2], wp[3], b_lo, b_hi);
    __syncthreads();
    *(half8*)&As[srow][shalf] = ma;
    *(half8*)&As[srow][shalf + 8] = mb2;
    *(half8*)&Bs[srow][shalf] = b_lo;
    *(half8*)&Bs[srow][shalf + 8] = b_hi;
    __syncthreads();
    half8 af[4], bfr[4];
#pragma unroll
    for (int mb = 0; mb < 4; mb++) af[mb] = *(const half8*)&As[wm + mb * 16 + l15][quad * 8];
#pragma unroll
    for (int nb = 0; nb < 4; nb++) bfr[nb] = *(const half8*)&Bs[wn + nb * 16 + l15][quad * 8];
#pragma unroll
    for (int mb = 0; mb < 4; mb++)
#pragma unroll
      for (int nb = 0; nb < 4; nb++)
        acc[mb][nb] = __builtin_amdgcn_mfma_f32_16x16x32_f16(af[mb], bfr[nb], acc[mb][nb], 0, 0, 0);
  }

  float* op = out + (size_t)bz * NN * CC;
#pragma unroll
  for (int mb = 0; mb < 4; mb++) {
    int nq0 = m0 + wm + mb * 16 + quad * 4;  // spatial
#pragma unroll
    for (int nb = 0; nb < 4; nb++) {
      int d = n0 + wn + nb * 16 + l15;
      float bv = bo[d];
      floatx4 pk;
      pk[0] = acc[mb][nb][0] + bv;
      pk[1] = acc[mb][nb][1] + bv;
      pk[2] = acc[mb][nb][2] + bv;
      pk[3] = acc[mb][nb][3] + bv;
      *(floatx4*)(op + (size_t)d * NN + nq0) = pk;
    }
  }
}

// ---------------------------------------------------------------------------
extern "C" void kernel_launch(void* const* d_in, const int* in_sizes, int n_in,
                              void* d_out, int out_size, void* d_ws, size_t ws_size,
                              hipStream_t stream) {
  const float* Fc = (const float*)d_in[0];
  const float* Fs = (const float*)d_in[1];
  const float* Wf = (const float*)d_in[2];
  const float* bf_ = (const float*)d_in[3];
  const float* Wg = (const float*)d_in[4];
  const float* bg = (const float*)d_in[5];
  const float* Wh = (const float*)d_in[6];
  const float* bh = (const float*)d_in[7];
  const float* Wo = (const float*)d_in[8];
  const float* bo = (const float*)d_in[9];

  char* ws = (char*)d_ws;
  const size_t sz = (size_t)NB * NN * CC * sizeof(_Float16);  // 8 MB per plane
  _Float16* Opart = (_Float16*)(ws + 0 * sz);  // planes 0..3 (split-K partials)
  _Float16* Qs = (_Float16*)(ws + 4 * sz);     // swizzled
  _Float16* Ks = (_Float16*)(ws + 5 * sz);
  _Float16* Vs = (_Float16*)(ws + 6 * sz);
  float2* Ml = (float2*)(ws + 7 * sz);         // 512 KB

  k_qkv<<<dim3(64, NB, 3), 256, 0, stream>>>(Fc, Fs, Wf, Wg, Wh, bf_, bg, bh, Qs, Ks, Vs);
  k_attn<<<dim3(32, 4, NB), 256, 0, stream>>>(Qs, Ks, Vs, Opart, Ml);
  k_out<<<dim3(64, NB), 256, 0, stream>>>(Opart, Ml, Wo, bo, (float*)d_out);
}

// Round 9
// 211.679 us; speedup vs baseline: 3.0652x; 1.0018x over previous
//
#include <hip/hip_runtime.h>
#include <stdint.h>

#define NB 4
#define CC 256
#define NN 4096   // H*W = 64*64
#define KITERS 32 // k-steps per attention chunk (chunk = 1024)
#define WAIT_LGKM0 0xC07F  // s_waitcnt lgkmcnt(0), vmcnt/expcnt untouched

typedef __attribute__((ext_vector_type(8))) _Float16 half8;   // MFMA A/B frag (4 VGPR)
typedef __attribute__((ext_vector_type(4))) _Float16 half4;   // 8B packed store
typedef __attribute__((ext_vector_type(2))) _Float16 half2v;
typedef __attribute__((ext_vector_type(4))) float floatx4;    // 16x16 acc
typedef __attribute__((ext_vector_type(16))) float float16v;  // 32x32 acc
typedef __attribute__((ext_vector_type(4))) int intx4;        // 16B copy

__device__ __forceinline__ void cvt16v(float4 a, float4 b, float4 c, float4 d,
                                       half8& lo, half8& hi) {
  lo[0] = (_Float16)a.x; lo[1] = (_Float16)a.y; lo[2] = (_Float16)a.z; lo[3] = (_Float16)a.w;
  lo[4] = (_Float16)b.x; lo[5] = (_Float16)b.y; lo[6] = (_Float16)b.z; lo[7] = (_Float16)b.w;
  hi[0] = (_Float16)c.x; hi[1] = (_Float16)c.y; hi[2] = (_Float16)c.z; hi[3] = (_Float16)c.w;
  hi[4] = (_Float16)d.x; hi[5] = (_Float16)d.y; hi[6] = (_Float16)d.z; hi[7] = (_Float16)d.w;
}

// ---------------------------------------------------------------------------
// Fused transpose + Q/K/V projections -> FRAG-MAJOR (swizzled) outputs.
// Reads F [b][c][n] fp32 directly; per k-iter transposes 32c x 128n via LDS.
// z=0: Q = Wf.Fc   z=1: K = Wg.Fs   z=2: Vt = (Fs^T.Wh^T)^T
// grid (64, NB, 3), 256 threads, 3 blocks/CU.  (unchanged from R8)
// ---------------------------------------------------------------------------
__global__ __launch_bounds__(256, 3) void k_qkv(const float* __restrict__ Fc,
                                                const float* __restrict__ Fs,
                                                const float* __restrict__ Wf,
                                                const float* __restrict__ Wg,
                                                const float* __restrict__ Wh,
                                                const float* __restrict__ bf,
                                                const float* __restrict__ bg,
                                                const float* __restrict__ bh,
                                                _Float16* __restrict__ Qs,
                                                _Float16* __restrict__ Ks,
                                                _Float16* __restrict__ Vs) {
  __shared__ float tmp[32][132];     // 16.9 KB fp32 transpose staging
  __shared__ _Float16 As[128][40];   // 10 KB
  __shared__ _Float16 Bs[128][40];   // 10 KB
  const int z = blockIdx.z, bz = blockIdx.y;
  const float* F = ((z == 0) ? Fc : Fs) + (size_t)bz * CC * NN;
  const float* W = (z == 0) ? Wf : ((z == 1) ? Wg : Wh);
  const float* bias = (z == 0) ? bf : ((z == 1) ? bg : bh);
  int mt, nt;
  if (z < 2) { mt = blockIdx.x >> 5; nt = blockIdx.x & 31; }  // M=d(256), N=n(4096)
  else       { mt = blockIdx.x >> 1; nt = blockIdx.x & 1;  }  // M=n(4096), N=d(256)
  const int m0 = mt * 128, n0 = nt * 128;
  const int xn0 = (z < 2) ? n0 : m0;  // spatial base of the F tile (X side)
  const int wd0 = (z < 2) ? m0 : n0;  // W row base (channel side)
  const int tid = threadIdx.x;
  const int wave = tid >> 6, lane = tid & 63, quad = lane >> 4, l15 = lane & 15;
  const int wm = (wave >> 1) * 64, wn = (wave & 1) * 64;

  floatx4 acc[4][4];
#pragma unroll
  for (int i = 0; i < 4; i++)
#pragma unroll
    for (int j = 0; j < 4; j++) acc[i][j] = (floatx4){0.f, 0.f, 0.f, 0.f};

  const int srow = tid >> 1, shalf = (tid & 1) * 16;   // W staging
  const int fc = tid >> 3, fn = (tid & 7) * 16;        // F load (c-row, n-off)
  const int xr = tid >> 1, xh = (tid & 1) * 16;        // transposed read

  float4 wr0, wr1, wr2, wr3, fr0, fr1, fr2, fr3;
  {
    const float4* wp = (const float4*)(W + (size_t)(wd0 + srow) * 256 + 0 + shalf);
    wr0 = wp[0]; wr1 = wp[1]; wr2 = wp[2]; wr3 = wp[3];
    const float4* fp = (const float4*)(F + (size_t)(0 + fc) * NN + xn0 + fn);
    fr0 = fp[0]; fr1 = fp[1]; fr2 = fp[2]; fr3 = fp[3];
  }

  for (int kk = 0; kk < 256; kk += 32) {
    __syncthreads();  // 1: prev frag+tmp reads done
    *(float4*)&tmp[fc][fn + 0] = fr0;
    *(float4*)&tmp[fc][fn + 4] = fr1;
    *(float4*)&tmp[fc][fn + 8] = fr2;
    *(float4*)&tmp[fc][fn + 12] = fr3;
    half8 w_lo, w_hi;
    cvt16v(wr0, wr1, wr2, wr3, w_lo, w_hi);
    if (z < 2) {
      *(half8*)&As[srow][shalf] = w_lo;
      *(half8*)&As[srow][shalf + 8] = w_hi;
    } else {
      *(half8*)&Bs[srow][shalf] = w_lo;
      *(half8*)&Bs[srow][shalf + 8] = w_hi;
    }
    __syncthreads();  // 2: tmp + W-side visible
    if (kk + 32 < 256) {  // prefetch next iter
      const float4* wp = (const float4*)(W + (size_t)(wd0 + srow) * 256 + kk + 32 + shalf);
      wr0 = wp[0]; wr1 = wp[1]; wr2 = wp[2]; wr3 = wp[3];
      const float4* fp = (const float4*)(F + (size_t)(kk + 32 + fc) * NN + xn0 + fn);
      fr0 = fp[0]; fr1 = fp[1]; fr2 = fp[2]; fr3 = fp[3];
    }
    half8 xlo, xhi;
#pragma unroll
    for (int i = 0; i < 8; i++) xlo[i] = (_Float16)tmp[xh + i][xr];
#pragma unroll
    for (int i = 0; i < 8; i++) xhi[i] = (_Float16)tmp[xh + 8 + i][xr];
    if (z < 2) {
      *(half8*)&Bs[xr][xh] = xlo;
      *(half8*)&Bs[xr][xh + 8] = xhi;
    } else {
      *(half8*)&As[xr][xh] = xlo;
      *(half8*)&As[xr][xh + 8] = xhi;
    }
    __syncthreads();  // 3: As/Bs complete
    half8 af[4], bfr[4];
#pragma unroll
    for (int mb = 0; mb < 4; mb++) af[mb] = *(const half8*)&As[wm + mb * 16 + l15][quad * 8];
#pragma unroll
    for (int nb = 0; nb < 4; nb++) bfr[nb] = *(const half8*)&Bs[wn + nb * 16 + l15][quad * 8];
#pragma unroll
    for (int mb = 0; mb < 4; mb++)
#pragma unroll
      for (int nb = 0; nb < 4; nb++)
        acc[mb][nb] = __builtin_amdgcn_mfma_f32_16x16x32_f16(af[mb], bfr[nb], acc[mb][nb], 0, 0, 0);
  }

  if (z < 2) {
    _Float16* op = (z == 0 ? Qs : Ks) + (size_t)bz * NN * CC;
#pragma unroll
    for (int mb = 0; mb < 4; mb++) {
      int d0 = m0 + wm + mb * 16 + quad * 4;
      float b0 = bias[d0], b1 = bias[d0 + 1], b2 = bias[d0 + 2], b3 = bias[d0 + 3];
      const int cs = d0 >> 4, hh = (d0 >> 3) & 1, j0 = d0 & 7;
#pragma unroll
      for (int nb = 0; nb < 4; nb++) {
        int n_ = n0 + wn + nb * 16 + l15;
        int kt = n_ >> 5, ql_ = n_ & 31;
        half4 pk;
        pk[0] = (_Float16)(acc[mb][nb][0] + b0);
        pk[1] = (_Float16)(acc[mb][nb][1] + b1);
        pk[2] = (_Float16)(acc[mb][nb][2] + b2);
        pk[3] = (_Float16)(acc[mb][nb][3] + b3);
        size_t idx = ((size_t)(kt * 16 + cs) * 64 + ql_ + 32 * hh) * 8 + j0;
        *(half4*)(op + idx) = pk;
      }
    }
  } else {
    _Float16* op = Vs + (size_t)bz * NN * CC;
#pragma unroll
    for (int mb = 0; mb < 4; mb++) {
      int nq0 = m0 + wm + mb * 16 + quad * 4;
      const int kt = nq0 >> 5, krel = nq0 & 31;
      const int hk = krel >> 4, hh = (krel >> 3) & 1, j0 = krel & 7;
#pragma unroll
      for (int nb = 0; nb < 4; nb++) {
        int d = n0 + wn + nb * 16 + l15;
        int ql_ = d & 31, g = (d >> 5) & 7;
        float bv = bias[d];
        half4 pk;
        pk[0] = (_Float16)(acc[mb][nb][0] + bv);
        pk[1] = (_Float16)(acc[mb][nb][1] + bv);
        pk[2] = (_Float16)(acc[mb][nb][2] + bv);
        pk[3] = (_Float16)(acc[mb][nb][3] + bv);
        size_t idx = (((size_t)(kt * 8 + g) * 2 + hk) * 64 + ql_ + 32 * hh) * 8 + j0;
        *(half4*)(op + idx) = pk;
      }
    }
  }
}

// ---------------------------------------------------------------------------
// Flash attention v8: frag-major LDS; MFMA burst reordered for chain
// independence (Oa[u] dep distance 16, s/s2 distance 4) — bit-exact vs v7.
// grid (32 qtiles, 4 chunks, NB), 256 threads, 2 barriers/iter.
// ---------------------------------------------------------------------------
__global__ __launch_bounds__(256, 2) void k_attn(const _Float16* __restrict__ Q,
                                                 const _Float16* __restrict__ K,
                                                 const _Float16* __restrict__ Vt,
                                                 _Float16* __restrict__ Opart,
                                                 float2* __restrict__ Ml) {
  __shared__ _Float16 smem[8192 * 3 + 4096];  // K 16KB | V dbuf 32KB | P 8KB
  const int tid = threadIdx.x;
  const int wave = tid >> 6, lane = tid & 63;
  _Float16* Kl = smem;
  _Float16* Plw = smem + 3 * 8192 + wave * 1024;  // [ks 2][lane 64][8]

  const int qt = blockIdx.x, ck = blockIdx.y, b = blockIdx.z;
  const int ql = lane & 31, h = lane >> 5;
  const int q0 = qt * 128 + wave * 32;
  const _Float16* Qb = Q + (size_t)b * NN * CC;
  const _Float16* Kb = K + (size_t)b * NN * CC;
  const _Float16* Vb = Vt + (size_t)b * NN * CC;
  const int kt_base = ck * (1024 / 32);

  const int ktq = q0 >> 5;
  half8 qf[16];
#pragma unroll
  for (int cs = 0; cs < 16; cs++)
    qf[cs] = *(const half8*)(Qb + ((size_t)(ktq * 16 + cs) * 64 + lane) * 8);

  float16v Oa[8];
#pragma unroll
  for (int g = 0; g < 8; g++)
#pragma unroll
    for (int i = 0; i < 16; i++) Oa[g][i] = 0.f;

  float m_run = -1e30f, l_run = 0.f;

  intx4 kpre[4], vpre[4];
  {
    const _Float16* Kt = Kb + (size_t)kt_base * 8192;
    const _Float16* Vtile = Vb + (size_t)kt_base * 8192;
#pragma unroll
    for (int p = 0; p < 4; p++) {
      kpre[p] = *(const intx4*)(Kt + tid * 8 + p * 2048);
      vpre[p] = *(const intx4*)(Vtile + tid * 8 + p * 2048);
    }
  }

  for (int t = 0; t < KITERS; t++) {
    const int vb = t & 1;
    _Float16* Vw = smem + (1 + vb) * 8192;
    __syncthreads();  // A
#pragma unroll
    for (int p = 0; p < 4; p++) {
      *(intx4*)(Kl + tid * 8 + p * 2048) = kpre[p];
      *(intx4*)(Vw + tid * 8 + p * 2048) = vpre[p];
    }
    __syncthreads();  // B
    if (t + 1 < KITERS) {
      const _Float16* Kt = Kb + (size_t)(kt_base + t + 1) * 8192;
      const _Float16* Vtile = Vb + (size_t)(kt_base + t + 1) * 8192;
#pragma unroll
      for (int p = 0; p < 4; p++) {
        kpre[p] = *(const intx4*)(Kt + tid * 8 + p * 2048);
        vpre[p] = *(const intx4*)(Vtile + tid * 8 + p * 2048);
      }
    }

    // ---- MFMA burst: S_i and PV_i interleaved; PV in ks-outer order:
    //   i<8: Oa[i]   += V[2i]  ·pf0     i>=8: Oa[i-8] += V[2(i-8)+1]·pf1
    // Per-chain accumulation order identical to v7 (bit-exact).
    float16v s, s2;
#pragma unroll
    for (int i = 0; i < 16; i++) { s[i] = 0.f; s2[i] = 0.f; }
    if (t > 0) {
      _Float16* Vr = smem + (1 + (vb ^ 1)) * 8192;
      half8 pf0 = *(const half8*)(Plw + lane * 8);
      half8 pf1 = *(const half8*)(Plw + 512 + lane * 8);
#pragma unroll
      for (int i = 0; i < 16; i++) {
        half8 kf = *(const half8*)(Kl + i * 512 + lane * 8);
        if (i & 1)
          s2 = __builtin_amdgcn_mfma_f32_32x32x16_f16(kf, qf[i], s2, 0, 0, 0);
        else
          s = __builtin_amdgcn_mfma_f32_32x32x16_f16(kf, qf[i], s, 0, 0, 0);
        const int u = i & 7, ks = i >> 3;
        half8 vf = *(const half8*)(Vr + (2 * u + ks) * 512 + lane * 8);
        Oa[u] = __builtin_amdgcn_mfma_f32_32x32x16_f16(vf, ks ? pf1 : pf0, Oa[u], 0, 0, 0);
      }
    } else {
#pragma unroll
      for (int cs = 0; cs < 16; cs += 2) {
        half8 kfa = *(const half8*)(Kl + cs * 512 + lane * 8);
        s = __builtin_amdgcn_mfma_f32_32x32x16_f16(kfa, qf[cs], s, 0, 0, 0);
        half8 kfb = *(const half8*)(Kl + (cs + 1) * 512 + lane * 8);
        s2 = __builtin_amdgcn_mfma_f32_32x32x16_f16(kfb, qf[cs + 1], s2, 0, 0, 0);
      }
    }
#pragma unroll
    for (int i = 0; i < 16; i++) s[i] += s2[i];

    // ---- lazy online softmax (per-lane), tree reductions
    float t0 = fmaxf(s[0], s[1]), t1 = fmaxf(s[2], s[3]);
    float t2 = fmaxf(s[4], s[5]), t3 = fmaxf(s[6], s[7]);
    float t4 = fmaxf(s[8], s[9]), t5 = fmaxf(s[10], s[11]);
    float t6 = fmaxf(s[12], s[13]), t7 = fmaxf(s[14], s[15]);
    t0 = fmaxf(t0, t1); t2 = fmaxf(t2, t3); t4 = fmaxf(t4, t5); t6 = fmaxf(t6, t7);
    float tmax = fmaxf(fmaxf(t0, t2), fmaxf(t4, t6));
    tmax = fmaxf(tmax, __shfl_xor(tmax, 32));
    bool need = tmax > m_run + 8.0f;
    if (__any((int)need)) {
      float mN = need ? tmax : m_run;
      float alpha = __expf(m_run - mN);
      m_run = mN;
      l_run *= alpha;
#pragma unroll
      for (int g = 0; g < 8; g++)
#pragma unroll
        for (int i = 0; i < 16; i++) Oa[g][i] *= alpha;
    }
#pragma unroll
    for (int i = 0; i < 16; i++) s[i] = __expf(s[i] - m_run);
    float u0 = (s[0] + s[1]) + (s[2] + s[3]);
    float u1 = (s[4] + s[5]) + (s[6] + s[7]);
    float u2 = (s[8] + s[9]) + (s[10] + s[11]);
    float u3 = (s[12] + s[13]) + (s[14] + s[15]);
    float ts = (u0 + u1) + (u2 + u3);
    ts += __shfl_xor(ts, 32);
    l_run += ts;
#pragma unroll
    for (int r = 0; r < 16; r += 2) {
      half2v pk;
      pk[0] = (_Float16)s[r];
      pk[1] = (_Float16)s[r + 1];
      int k = (r & 3) + 8 * (r >> 2) + 4 * h;
      *(half2v*)(Plw + (k >> 4) * 512 + (ql + 32 * ((k >> 3) & 1)) * 8 + (k & 7)) = pk;
    }
  }

  // ---- tail: PV for last tile (ks-outer, same per-chain order)
  {
    _Float16* Vr = smem + (1 + ((KITERS - 1) & 1)) * 8192;
    half8 pf0 = *(const half8*)(Plw + lane * 8);
    half8 pf1 = *(const half8*)(Plw + 512 + lane * 8);
#pragma unroll
    for (int u = 0; u < 8; u++) {
      half8 vfa = *(const half8*)(Vr + (2 * u) * 512 + lane * 8);
      Oa[u] = __builtin_amdgcn_mfma_f32_32x32x16_f16(vfa, pf0, Oa[u], 0, 0, 0);
    }
#pragma unroll
    for (int u = 0; u < 8; u++) {
      half8 vfb = *(const half8*)(Vr + (2 * u + 1) * 512 + lane * 8);
      Oa[u] = __builtin_amdgcn_mfma_f32_32x32x16_f16(vfb, pf1, Oa[u], 0, 0, 0);
    }
  }

  // ---- epilogue: normalize, per-wave LDS transpose, coalesced store
  float invl = 1.f / l_run;
  __syncthreads();
  float* ot = (float*)smem + wave * (32 * 33);
  _Float16* Opb = Opart + ((size_t)ck * NB + b) * NN * CC;
  const int qr = lane >> 1;
  const int chalf = (lane & 1) * 16;
#pragma unroll
  for (int g = 0; g < 8; g++) {
#pragma unroll
    for (int r = 0; r < 16; r++)
      ot[((r & 3) + 8 * (r >> 2) + 4 * h) * 33 + ql] = Oa[g][r] * invl;
    __builtin_amdgcn_s_waitcnt(WAIT_LGKM0);
    half8 o0, o1;
#pragma unroll
    for (int i = 0; i < 8; i++) o0[i] = (_Float16)ot[(chalf + i) * 33 + qr];
#pragma unroll
    for (int i = 0; i < 8; i++) o1[i] = (_Float16)ot[(chalf + 8 + i) * 33 + qr];
    _Float16* gp = Opb + (size_t)(q0 + qr) * CC + g * 32 + chalf;
    *(half8*)gp = o0;
    *(half8*)(gp + 8) = o1;
    __builtin_amdgcn_s_waitcnt(WAIT_LGKM0);
  }
  if (h == 0) {
    float2 ml; ml.x = m_run; ml.y = l_run;
    Ml[((size_t)ck * NB + b) * NN + q0 + ql] = ml;
  }
}

// ---------------------------------------------------------------------------
// Final conv with fused split-K merge, re-tiled 64x128 for 2 blocks/CU.
// out[b][d][n] fp32 = Wo . O^T + bo. grid (128, NB), 256 threads.
// Wave layout: wave owns n-slice wn = wave*32 (2 n-subtiles), all 4 m-subtiles.
// ---------------------------------------------------------------------------
__global__ __launch_bounds__(256, 2) void k_out(const _Float16* __restrict__ Opart,
                                                const float2* __restrict__ Ml,
                                                const float* __restrict__ Wo,
                                                const float* __restrict__ bo,
                                                float* __restrict__ out) {
  __shared__ _Float16 As[64][40];    // 5 KB  (merged O rows)
  __shared__ _Float16 Bs[128][40];   // 10 KB (Wo rows)
  const int bz = blockIdx.y;
  const int mt = blockIdx.x >> 1, nt = blockIdx.x & 1;  // 64 mtiles x 2 ntiles
  const int m0 = mt * 64, n0 = nt * 128;
  const int tid = threadIdx.x;
  const int wave = tid >> 6, lane = tid & 63, quad = lane >> 4, l15 = lane & 15;
  const int wn = wave * 32;

  floatx4 acc[4][2];
#pragma unroll
  for (int i = 0; i < 4; i++)
#pragma unroll
    for (int j = 0; j < 2; j++) acc[i][j] = (floatx4){0.f, 0.f, 0.f, 0.f};

  const int arow = tid >> 2, acol = (tid & 3) * 8;   // A: 64 rows x 32 c
  const int brow = tid >> 1, bcol = (tid & 1) * 16;  // B: 128 rows x 32 c

  // merge weights for this thread's fixed row q = m0 + arow
  const size_t qi = (size_t)bz * NN + m0 + arow;
  float2 a0 = Ml[qi], a1 = Ml[(size_t)NB * NN + qi];
  float2 a2 = Ml[(size_t)2 * NB * NN + qi], a3 = Ml[(size_t)3 * NB * NN + qi];
  float M = fmaxf(fmaxf(a0.x, a1.x), fmaxf(a2.x, a3.x));
  float w0 = __expf(a0.x - M) * a0.y, w1 = __expf(a1.x - M) * a1.y;
  float w2 = __expf(a2.x - M) * a2.y, w3 = __expf(a3.x - M) * a3.y;
  float inv = 1.f / (w0 + w1 + w2 + w3);
  w0 *= inv; w1 *= inv; w2 *= inv; w3 *= inv;
  const size_t ps = (size_t)NB * NN * CC;
  const _Float16* prow = Opart + qi * CC;

  // preload kk=0
  half8 pA0, pA1, pA2, pA3;
  float4 wr0, wr1, wr2, wr3;
  {
    const _Float16* pr = prow + acol;
    pA0 = *(const half8*)pr;
    pA1 = *(const half8*)(pr + ps);
    pA2 = *(const half8*)(pr + 2 * ps);
    pA3 = *(const half8*)(pr + 3 * ps);
    const float4* wp = (const float4*)(Wo + (size_t)(n0 + brow) * 256 + bcol);
    wr0 = wp[0]; wr1 = wp[1]; wr2 = wp[2]; wr3 = wp[3];
  }

  for (int kk = 0; kk < 256; kk += 32) {
    half8 ma;
#pragma unroll
    for (int i = 0; i < 8; i++)
      ma[i] = (_Float16)(w0 * (float)pA0[i] + w1 * (float)pA1[i] +
                         w2 * (float)pA2[i] + w3 * (float)pA3[i]);
    half8 b_lo, b_hi;
    cvt16v(wr0, wr1, wr2, wr3, b_lo, b_hi);
    __syncthreads();  // prev frag reads done
    *(half8*)&As[arow][acol] = ma;
    *(half8*)&Bs[brow][bcol] = b_lo;
    *(half8*)&Bs[brow][bcol + 8] = b_hi;
    __syncthreads();  // tiles visible
    if (kk + 32 < 256) {  // prefetch next slice
      const _Float16* pr = prow + kk + 32 + acol;
      pA0 = *(const half8*)pr;
      pA1 = *(const half8*)(pr + ps);
      pA2 = *(const half8*)(pr + 2 * ps);
      pA3 = *(const half8*)(pr + 3 * ps);
      const float4* wp = (const float4*)(Wo + (size_t)(n0 + brow) * 256 + kk + 32 + bcol);
      wr0 = wp[0]; wr1 = wp[1]; wr2 = wp[2]; wr3 = wp[3];
    }
    half8 af[4], bfr[2];
#pragma unroll
    for (int mb = 0; mb < 4; mb++) af[mb] = *(const half8*)&As[mb * 16 + l15][quad * 8];
#pragma unroll
    for (int nb = 0; nb < 2; nb++) bfr[nb] = *(const half8*)&Bs[wn + nb * 16 + l15][quad * 8];
#pragma unroll
    for (int mb = 0; mb < 4; mb++)
#pragma unroll
      for (int nb = 0; nb < 2; nb++)
        acc[mb][nb] = __builtin_amdgcn_mfma_f32_16x16x32_f16(af[mb], bfr[nb], acc[mb][nb], 0, 0, 0);
  }

  float* op = out + (size_t)bz * NN * CC;
#pragma unroll
  for (int mb = 0; mb < 4; mb++) {
    int nq0 = m0 + mb * 16 + quad * 4;  // spatial
#pragma unroll
    for (int nb = 0; nb < 2; nb++) {
      int d = n0 + wn + nb * 16 + l15;
      float bv = bo[d];
      floatx4 pk;
      pk[0] = acc[mb][nb][0] + bv;
      pk[1] = acc[mb][nb][1] + bv;
      pk[2] = acc[mb][nb][2] + bv;
      pk[3] = acc[mb][nb][3] + bv;
      *(floatx4*)(op + (size_t)d * NN + nq0) = pk;
    }
  }
}

// ---------------------------------------------------------------------------
extern "C" void kernel_launch(void* const* d_in, const int* in_sizes, int n_in,
                              void* d_out, int out_size, void* d_ws, size_t ws_size,
                              hipStream_t stream) {
  const float* Fc = (const float*)d_in[0];
  const float* Fs = (const float*)d_in[1];
  const float* Wf = (const float*)d_in[2];
  const float* bf_ = (const float*)d_in[3];
  const float* Wg = (const float*)d_in[4];
  const float* bg = (const float*)d_in[5];
  const float* Wh = (const float*)d_in[6];
  const float* bh = (const float*)d_in[7];
  const float* Wo = (const float*)d_in[8];
  const float* bo = (const float*)d_in[9];

  char* ws = (char*)d_ws;
  const size_t sz = (size_t)NB * NN * CC * sizeof(_Float16);  // 8 MB per plane
  _Float16* Opart = (_Float16*)(ws + 0 * sz);  // planes 0..3 (split-K partials)
  _Float16* Qs = (_Float16*)(ws + 4 * sz);     // swizzled
  _Float16* Ks = (_Float16*)(ws + 5 * sz);
  _Float16* Vs = (_Float16*)(ws + 6 * sz);
  float2* Ml = (float2*)(ws + 7 * sz);         // 512 KB

  k_qkv<<<dim3(64, NB, 3), 256, 0, stream>>>(Fc, Fs, Wf, Wg, Wh, bf_, bg, bh, Qs, Ks, Vs);
  k_attn<<<dim3(32, 4, NB), 256, 0, stream>>>(Qs, Ks, Vs, Opart, Ml);
  k_out<<<dim3(128, NB), 256, 0, stream>>>(Opart, Ml, Wo, bo, (float*)d_out);
}